// Round 1
// 600.422 us; speedup vs baseline: 1.1094x; 1.1094x over previous
//
#include <hip/hip_runtime.h>
#include <hip/hip_bf16.h>
#include <math.h>

#define B_ 4
#define L_ 2048
#define D_ 2048
#define M_ 64
#define R_ 128
#define NTOK (B_*L_)
#define SCALE_ 0.125f
#define C_ 16
#define NCH (L_/C_)

typedef __attribute__((ext_vector_type(8))) short short8;
typedef __attribute__((ext_vector_type(4))) float f32x4;

// lgkmcnt-only barrier: LDS visibility without draining vmcnt, so global
// prefetch loads stay in flight across chunk phases (counted-vmcnt principle).
#define BAR() asm volatile("s_waitcnt lgkmcnt(0)\n\ts_barrier" ::: "memory")

__device__ __forceinline__ unsigned short f2bfu(float v) {
    union { float f; unsigned u; } a; a.f = v;
    unsigned r = a.u + 0x7fffu + ((a.u >> 16) & 1u);
    return (unsigned short)(r >> 16);
}
__device__ __forceinline__ float bfu2f(unsigned short h) {
    union { unsigned u; float f; } a; a.u = ((unsigned)h) << 16;
    return a.f;
}

// ---------------- 1. causal depthwise conv (W=4) + silu ----------------
__global__ __launch_bounds__(256) void k_conv(const float* __restrict__ x,
    const float* __restrict__ cw, const float* __restrict__ cb,
    float* __restrict__ shift)
{
    size_t idx = (size_t)blockIdx.x * 256 + threadIdx.x;
    int d = (int)(idx % D_);
    size_t n = idx / D_;
    int l = (int)(n % L_);
    float y = cb[d];
    const float* wp = cw + (size_t)d * 4;
#pragma unroll
    for (int i = 0; i < 4; i++) {
        int ll = l - 3 + i;
        if (ll >= 0) y = fmaf(x[idx + (size_t)(i - 3) * D_], wp[i], y);
    }
    shift[idx] = y / (1.f + expf(-y));
}

// ---------------- weight cast fp32 -> bf16 ----------------
__device__ __forceinline__ unsigned pkbf(float a, float b) {
    union { __hip_bfloat162 h; unsigned u; } cv;
    cv.h = __float22bfloat162_rn(make_float2(a, b));
    return cv.u;
}

__global__ __launch_bounds__(256) void k_castw(
    const float* __restrict__ s0, const float* __restrict__ s1,
    const float* __restrict__ s2, const float* __restrict__ s3,
    unsigned short* __restrict__ d0, unsigned short* __restrict__ d1,
    unsigned short* __restrict__ d2, unsigned short* __restrict__ d3)
{
    int which = blockIdx.x >> 8;
    int idx = ((blockIdx.x & 255) * 256 + threadIdx.x) * 4;
    const float* s = which == 0 ? s0 : which == 1 ? s1 : which == 2 ? s2 : s3;
    unsigned short* d = which == 0 ? d0 : which == 1 ? d1 : which == 2 ? d2 : d3;
    float4 v = *(const float4*)(s + idx);
    uint2 o;
    o.x = pkbf(v.x, v.y);
    o.y = pkbf(v.z, v.w);
    *(uint2*)(d + idx) = o;
}

// ---------------- bf16 MFMA NT GEMM (unchanged) ----------------
__global__ __launch_bounds__(256) void k_mfma_nt(
    const float* __restrict__ A, const unsigned short* __restrict__ Bb,
    float* __restrict__ out, int K, int ldo, int jo,
    int mode, const float* __restrict__ bias, const float* __restrict__ xmul)
{
    __shared__ unsigned short As[128 * 32];
    __shared__ unsigned short Bs[128 * 32];
    int tid = threadIdx.x;
    int n0 = blockIdx.x * 128;
    int jblk = blockIdx.y * 128;
    int wave = tid >> 6, lane = tid & 63;
    int quad = lane >> 4, lcol = lane & 15;
    int wrow = (wave >> 1) * 64, wcol = (wave & 1) * 64;

    f32x4 acc[4][4];
#pragma unroll
    for (int i = 0; i < 4; i++)
#pragma unroll
        for (int j = 0; j < 4; j++) acc[i][j] = {0.f, 0.f, 0.f, 0.f};

    for (int k0 = 0; k0 < K; k0 += 32) {
        float4 a0[2][2];
        uint4 bv[2];
#pragma unroll
        for (int p = 0; p < 2; p++) {
            int idx = p * 256 + tid;
            int row = idx >> 2, sub = idx & 3;
            const float* ap = A + (size_t)(n0 + row) * K + k0 + sub * 8;
            a0[p][0] = *(const float4*)ap;
            a0[p][1] = *(const float4*)(ap + 4);
            bv[p] = *(const uint4*)(Bb + (size_t)(jblk + row) * K + k0 + sub * 8);
        }
        __syncthreads();
#pragma unroll
        for (int p = 0; p < 2; p++) {
            int idx = p * 256 + tid;
            int row = idx >> 2, sub = idx & 3;
            uint4 w;
            w.x = pkbf(a0[p][0].x, a0[p][0].y);
            w.y = pkbf(a0[p][0].z, a0[p][0].w);
            w.z = pkbf(a0[p][1].x, a0[p][1].y);
            w.w = pkbf(a0[p][1].z, a0[p][1].w);
            *(uint4*)&As[row * 32 + sub * 8] = w;
            *(uint4*)&Bs[row * 32 + sub * 8] = bv[p];
        }
        __syncthreads();
        short8 af[4], bfr[4];
#pragma unroll
        for (int i = 0; i < 4; i++)
            af[i] = *(short8*)&As[(wrow + i * 16 + lcol) * 32 + quad * 8];
#pragma unroll
        for (int j = 0; j < 4; j++)
            bfr[j] = *(short8*)&Bs[(wcol + j * 16 + lcol) * 32 + quad * 8];
#pragma unroll
        for (int i = 0; i < 4; i++)
#pragma unroll
            for (int j = 0; j < 4; j++)
                acc[i][j] = __builtin_amdgcn_mfma_f32_16x16x32_bf16(
                    af[i], bfr[j], acc[i][j], 0, 0, 0);
    }

#pragma unroll
    for (int i = 0; i < 4; i++) {
#pragma unroll
        for (int j = 0; j < 4; j++) {
#pragma unroll
            for (int q = 0; q < 4; q++) {
                int row = wrow + i * 16 + quad * 4 + q;
                int col = wcol + j * 16 + lcol;
                int n = n0 + row;
                int jc = jblk + col;
                float val = acc[i][j][q];
                if (mode == 1) {
                    val += bias[jc];
                    val = 1.f / (1.f + expf(-val));
                    val *= xmul[(size_t)n * ldo + jo + jc];
                }
                out[(size_t)n * ldo + jo + jc] = val;
            }
        }
    }
}

// ---------------- 5. per-chunk gate prep: decay transform hoisted here ----
// One block per (batch, chunk): computes r,k,gates per token AND the chunk
// decay transform (cumulative lambda), emitting bf16 rt/kd/kc + f32 aC.
// This removes the exp-heavy decay phase (done 64x redundantly before) from
// k_chunk's serial loop. Identical arithmetic/rounding as the old in-loop code.
__global__ __launch_bounds__(256) void k_prep(const float* __restrict__ rkmg,
    const float* __restrict__ mb,
    unsigned short* __restrict__ Rt, unsigned short* __restrict__ Kd,
    unsigned short* __restrict__ Kc, float* __restrict__ Ac)
{
    __shared__ float seg[4 * 64];
    int blk = blockIdx.x;                 // b*NCH + chunk
    int sg = threadIdx.x >> 6, mm = threadIdx.x & 63;
    int n0 = blk * 16 + sg * 4;           // global token base for this group

    float rr[4], kk[4], lamr[4];
    float csum = 0.f;
#pragma unroll
    for (int j = 0; j < 4; j++) {
        const float* row = rkmg + (size_t)(n0 + j) * 256;
        float r   = row[mm];
        float k   = row[64 + mm];
        float mg1 = row[128 + mm] + mb[mm];
        float mg2 = row[192 + mm] + mb[64 + mm];
        float sel = (mg1 > 20.f) ? mg1 : log1pf(expf(mg1));
        float tau = 1.f / (1.f + expf(-mg2));
        float it  = expf(tau * logf(sel));
        float g   = -sel * tau;
        float s2  = k * k;
#pragma unroll
        for (int off = 32; off >= 1; off >>= 1) s2 += __shfl_xor(s2, off, 64);
        float kn = k / fmaxf(sqrtf(s2), 1e-12f);
        rr[j] = r;
        kk[j] = kn * it;
        csum += g;
        lamr[j] = csum;                  // inclusive cumsum within group
    }
    seg[sg * 64 + mm] = csum;
    __syncthreads();
    float off = 0.f, tot = 0.f;
#pragma unroll
    for (int s = 0; s < 4; s++) {
        float v = seg[s * 64 + mm];
        if (s < sg) off += v;
        tot += v;
    }
    size_t obase = (size_t)blk * 1024;
    unsigned short kcp[4];
#pragma unroll
    for (int j = 0; j < 4; j++) {
        float lam = off + lamr[j];
        Rt[obase + (size_t)(sg * 4 + j) * 64 + mm] = f2bfu(rr[j] * expf(lam));
        Kd[obase + (size_t)(sg * 4 + j) * 64 + mm] = f2bfu(kk[j] * expf(-lam));
        kcp[j] = f2bfu(kk[j] * expf(tot - lam));
    }
    ushort4 kc4;
    kc4.x = kcp[0]; kc4.y = kcp[1]; kc4.z = kcp[2]; kc4.w = kcp[3];
    *(ushort4*)&Kc[obase + (size_t)mm * 16 + sg * 4] = kc4;   // [chunk][m][16]
    if (sg == 0) Ac[(size_t)blk * 64 + mm] = expf(tot);
}

// ---------------- 6. chunked recurrence: 2 raw barriers / chunk ----------
// block = (b, 32-d slice): 256 blocks x 256 thr (4 waves), 1 block/CU.
// Per chunk: stage bf16 rt/kd/kcT/U/aC -> BAR -> phase1 {waves0-1: r~@S
// partial-O, wave0: P=mask(rt@kd^T); waves2-3: S' = aC*S + kcT@U (pong)}
// -> BAR -> tail {waves0-1: O += P@U, store}.  U double-buffered so no
// end-of-loop barrier; prefetch (incl. shift) stays in flight across BARs.
__global__ __launch_bounds__(256) void k_chunk(
    const unsigned short* __restrict__ Rt, const unsigned short* __restrict__ Kd,
    const unsigned short* __restrict__ Kc, const float* __restrict__ Ac,
    const float* __restrict__ u, const float* __restrict__ shift,
    const float* __restrict__ rw, float* __restrict__ out)
{
    __shared__ __align__(16) unsigned short UTh[2][32 * 40]; // [d][s] dbuf
    __shared__ __align__(16) unsigned short UTl[2][32 * 40];
    __shared__ __align__(16) unsigned short rt[16 * 72];     // [t][m]
    __shared__ __align__(16) unsigned short kd[16 * 72];     // [s][m]
    __shared__ __align__(16) unsigned short kcT[64 * 40];    // [m][s] K-pad
    __shared__ __align__(16) unsigned short Pl[16 * 40];     // [t][s] K-pad
    __shared__ __align__(16) unsigned short STh[2][32 * 72]; // [d][m] pingpong
    __shared__ __align__(16) unsigned short STl[2][32 * 72];
    __shared__ __align__(16) float aCs[64];

    int tid = threadIdx.x;
    int wave = tid >> 6, lane = tid & 63;
    int quad = lane >> 4, l15 = lane & 15;
    int b = blockIdx.x & 3, slice = blockIdx.x >> 2;
    int d0 = slice * 32;

    // zero-init pads + initial state (pads never rewritten)
    {
        unsigned short* p0 = &UTh[0][0];
        unsigned short* p1 = &UTl[0][0];
        for (int i = tid; i < 2 * 32 * 40; i += 256) { p0[i] = 0; p1[i] = 0; }
        for (int i = tid; i < 64 * 40; i += 256) kcT[i] = 0;
        for (int i = tid; i < 16 * 40; i += 256) Pl[i] = 0;
        unsigned short* s0 = &STh[0][0];
        unsigned short* s1 = &STl[0][0];
        for (int i = tid; i < 2 * 32 * 72; i += 256) { s0[i] = 0; s1[i] = 0; }
    }

    size_t cbase = (size_t)b * NCH * 1024;
    size_t ubase = (size_t)b * L_ * D_ + d0;

    float rwv = 0.f;
    if (wave < 2) rwv = rw[d0 + wave * 16 + l15];

    // ---- prefetch chunk 0 ----
    ushort4 rtv = *(const ushort4*)(Rt + cbase + (size_t)tid * 4);
    ushort4 kdv = *(const ushort4*)(Kd + cbase + (size_t)tid * 4);
    ushort4 kcv = *(const ushort4*)(Kc + cbase + (size_t)tid * 4);
    float uv0 = u[ubase + (size_t)(tid >> 5) * D_ + (tid & 31)];
    float uv1 = u[ubase + (size_t)(8 + (tid >> 5)) * D_ + (tid & 31)];
    float acv = 0.f;
    if (tid < 64) acv = Ac[(size_t)b * NCH * 64 + tid];
    size_t sbase = ubase + (size_t)(wave & 1) * 16 + l15 + (size_t)(quad * 4) * D_;
    float sv0 = 0.f, sv1 = 0.f, sv2 = 0.f, sv3 = 0.f;
    float svn0 = 0.f, svn1 = 0.f, svn2 = 0.f, svn3 = 0.f;
    if (wave < 2) {
        sv0 = shift[sbase];
        sv1 = shift[sbase + D_];
        sv2 = shift[sbase + 2 * D_];
        sv3 = shift[sbase + 3 * D_];
    }

    BAR();   // zero-init visible

    f32x4 zz = {0.f, 0.f, 0.f, 0.f};

    for (int c = 0; c < NCH; c++) {
        int ping = c & 1;

        // ---- stage chunk c ----
        *(ushort4*)&rt[(tid >> 4) * 72 + (tid & 15) * 4] = rtv;
        *(ushort4*)&kd[(tid >> 4) * 72 + (tid & 15) * 4] = kdv;
        *(ushort4*)&kcT[(tid >> 2) * 40 + (tid & 3) * 4] = kcv;
        {
            int tt = tid >> 5, dd = tid & 31;
            unsigned short h0 = f2bfu(uv0);
            UTh[ping][dd * 40 + tt] = h0;
            UTl[ping][dd * 40 + tt] = f2bfu(uv0 - bfu2f(h0));
            unsigned short h1 = f2bfu(uv1);
            UTh[ping][dd * 40 + 8 + tt] = h1;
            UTl[ping][dd * 40 + 8 + tt] = f2bfu(uv1 - bfu2f(h1));
        }
        if (tid < 64) aCs[tid] = acv;

        // ---- issue prefetch for chunk c+1 (drains across the barriers) ----
        if (c + 1 < NCH) {
            size_t g0 = cbase + (size_t)(c + 1) * 1024 + (size_t)tid * 4;
            rtv = *(const ushort4*)(Rt + g0);
            kdv = *(const ushort4*)(Kd + g0);
            kcv = *(const ushort4*)(Kc + g0);
            size_t un = ubase + (size_t)(c + 1) * C_ * D_;
            uv0 = u[un + (size_t)(tid >> 5) * D_ + (tid & 31)];
            uv1 = u[un + (size_t)(8 + (tid >> 5)) * D_ + (tid & 31)];
            if (tid < 64) acv = Ac[(size_t)(b * NCH + c + 1) * 64 + tid];
            if (wave < 2) {
                size_t s0 = sbase + (size_t)(c + 1) * C_ * D_;
                svn0 = shift[s0];
                svn1 = shift[s0 + D_];
                svn2 = shift[s0 + 2 * D_];
                svn3 = shift[s0 + 3 * D_];
            }
        }

        BAR();   // stage visible

        // ---- phase 1 ----
        short8 af0, af1;
        f32x4 oA, oB;
        if (wave < 2) {
            int h = wave;
            af0 = *(const short8*)&rt[l15 * 72 + quad * 8];
            af1 = *(const short8*)&rt[l15 * 72 + 32 + quad * 8];
            const unsigned short* sbh = &STh[ping][(h * 16 + l15) * 72];
            const unsigned short* sbl = &STl[ping][(h * 16 + l15) * 72];
            short8 sh0 = *(const short8*)&sbh[quad * 8];
            short8 sh1 = *(const short8*)&sbh[32 + quad * 8];
            short8 sl0 = *(const short8*)&sbl[quad * 8];
            short8 sl1 = *(const short8*)&sbl[32 + quad * 8];
            oA = zz;
            oB = zz;
            oA = __builtin_amdgcn_mfma_f32_16x16x32_bf16(af0, sh0, oA, 0, 0, 0);
            oB = __builtin_amdgcn_mfma_f32_16x16x32_bf16(af0, sl0, oB, 0, 0, 0);
            oA = __builtin_amdgcn_mfma_f32_16x16x32_bf16(af1, sh1, oA, 0, 0, 0);
            oB = __builtin_amdgcn_mfma_f32_16x16x32_bf16(af1, sl1, oB, 0, 0, 0);
            if (wave == 0) {
                short8 b0 = *(const short8*)&kd[l15 * 72 + quad * 8];
                short8 b1 = *(const short8*)&kd[l15 * 72 + 32 + quad * 8];
                f32x4 p1 = zz, p2 = zz;
                p1 = __builtin_amdgcn_mfma_f32_16x16x32_bf16(af0, b0, p1, 0, 0, 0);
                p2 = __builtin_amdgcn_mfma_f32_16x16x32_bf16(af1, b1, p2, 0, 0, 0);
#pragma unroll
                for (int q = 0; q < 4; q++) {
                    int t = quad * 4 + q;
                    float v = (l15 <= t) ? (p1[q] + p2[q]) : 0.f;
                    Pl[t * 40 + l15] = f2bfu(v);
                }
            }
        } else {
            // S' = aC*S + kcT@U for d-half h (into pong)
            int h = wave - 2;
            short8 uh = *(const short8*)&UTh[ping][(h * 16 + l15) * 40 + quad * 8];
            short8 ul = *(const short8*)&UTl[ping][(h * 16 + l15) * 40 + quad * 8];
#pragma unroll
            for (int mt = 0; mt < 4; mt++) {
                int sidx = (h * 16 + l15) * 72 + mt * 16 + quad * 4;
                ushort4 ch = *(const ushort4*)&STh[ping][sidx];
                ushort4 cl = *(const ushort4*)&STl[ping][sidx];
                f32x4 a4 = *(const f32x4*)&aCs[mt * 16 + quad * 4];
                f32x4 sacc;
                sacc[0] = (bfu2f(ch.x) + bfu2f(cl.x)) * a4[0];
                sacc[1] = (bfu2f(ch.y) + bfu2f(cl.y)) * a4[1];
                sacc[2] = (bfu2f(ch.z) + bfu2f(cl.z)) * a4[2];
                sacc[3] = (bfu2f(ch.w) + bfu2f(cl.w)) * a4[3];
                short8 ka = *(const short8*)&kcT[(mt * 16 + l15) * 40 + quad * 8];
                sacc = __builtin_amdgcn_mfma_f32_16x16x32_bf16(ka, uh, sacc, 0, 0, 0);
                sacc = __builtin_amdgcn_mfma_f32_16x16x32_bf16(ka, ul, sacc, 0, 0, 0);
                ushort4 nh, nl;
                unsigned short hq;
                hq = f2bfu(sacc[0]); nh.x = hq; nl.x = f2bfu(sacc[0] - bfu2f(hq));
                hq = f2bfu(sacc[1]); nh.y = hq; nl.y = f2bfu(sacc[1] - bfu2f(hq));
                hq = f2bfu(sacc[2]); nh.z = hq; nl.z = f2bfu(sacc[2] - bfu2f(hq));
                hq = f2bfu(sacc[3]); nh.w = hq; nl.w = f2bfu(sacc[3] - bfu2f(hq));
                *(ushort4*)&STh[ping ^ 1][sidx] = nh;
                *(ushort4*)&STl[ping ^ 1][sidx] = nl;
            }
        }

        BAR();   // Pl + ST[pong] visible; all phase-1 LDS reads drained

        // ---- tail: O = SCALE*(P@U + rt@S) + shift*rw ----
        if (wave < 2) {
            int h = wave;
            short8 pA = *(const short8*)&Pl[l15 * 40 + quad * 8];
            short8 uh = *(const short8*)&UTh[ping][(h * 16 + l15) * 40 + quad * 8];
            short8 ul = *(const short8*)&UTl[ping][(h * 16 + l15) * 40 + quad * 8];
            oA = __builtin_amdgcn_mfma_f32_16x16x32_bf16(pA, uh, oA, 0, 0, 0);
            oB = __builtin_amdgcn_mfma_f32_16x16x32_bf16(pA, ul, oB, 0, 0, 0);
            size_t oa = ubase + (size_t)(c * C_ + quad * 4) * D_ + h * 16 + l15;
            out[oa]          = SCALE_ * (oA[0] + oB[0]) + sv0 * rwv;
            out[oa + D_]     = SCALE_ * (oA[1] + oB[1]) + sv1 * rwv;
            out[oa + 2 * D_] = SCALE_ * (oA[2] + oB[2]) + sv2 * rwv;
            out[oa + 3 * D_] = SCALE_ * (oA[3] + oB[3]) + sv3 * rwv;
        }
        sv0 = svn0; sv1 = svn1; sv2 = svn2; sv3 = svn3;
        // No barrier here: next stage only writes UT[ping^1]/rt/kd/kcT/aCs,
        // whose phase-1 readers drained at the mid barrier; Pl/UT[ping]
        // readers (this tail) drain at the next stage barrier before wave0
        // rewrites Pl (it can only pass that barrier after all waves arrive).
    }
}

// ---------------- launcher ----------------
extern "C" void kernel_launch(void* const* d_in, const int* in_sizes, int n_in,
                              void* d_out, int out_size, void* d_ws, size_t ws_size,
                              hipStream_t stream)
{
    const float* x   = (const float*)d_in[0];
    const float* cw  = (const float*)d_in[1];
    const float* cb  = (const float*)d_in[2];
    const float* ipw = (const float*)d_in[3];
    const float* w0  = (const float*)d_in[4];
    const float* w1  = (const float*)d_in[5];
    const float* b1  = (const float*)d_in[6];
    const float* mw  = (const float*)d_in[7];
    const float* mb  = (const float*)d_in[8];
    const float* rw  = (const float*)d_in[9];
    float* out = (float*)d_out;

    float* ws    = (float*)d_ws;
    float* shift = ws;
    float* u     = shift + (size_t)NTOK * D_;
    float* rkmg  = u + (size_t)NTOK * D_;
    float* t1    = rkmg + (size_t)NTOK * 256;
    float* Ac    = t1 + (size_t)NTOK * R_;
    unsigned short* Rt    = (unsigned short*)(Ac + (size_t)B_ * NCH * 64);
    unsigned short* Kd    = Rt + (size_t)NTOK * 64;
    unsigned short* Kc    = Kd + (size_t)NTOK * 64;
    unsigned short* Wcatb = Kc + (size_t)NTOK * 64;
    unsigned short* w0b   = Wcatb + 256 * 2048;
    unsigned short* w1b   = w0b + 128 * 2048;

    k_conv<<<(NTOK * (size_t)D_) / 256, 256, 0, stream>>>(x, cw, cb, shift);

    k_castw<<<1024, 256, 0, stream>>>(ipw, mw, w0, w1,
                                      Wcatb, Wcatb + 128 * 2048, w0b, w1b);

    k_mfma_nt<<<dim3(64, 2), 256, 0, stream>>>(shift, Wcatb, rkmg, D_, 256, 0,
                                               0, nullptr, nullptr);
    k_mfma_nt<<<dim3(64, 1), 256, 0, stream>>>(x, w0b, t1, D_, R_, 0,
                                               0, nullptr, nullptr);
    k_mfma_nt<<<dim3(64, 16), 256, 0, stream>>>(t1, w1b, u, R_, D_, 0,
                                                1, b1, x);

    k_prep<<<B_ * NCH, 256, 0, stream>>>(rkmg, mb, Rt, Kd, Kc, Ac);

    k_chunk<<<256, 256, 0, stream>>>(Rt, Kd, Kc, Ac, u, shift, rw, out);
}

// Round 2
// 497.192 us; speedup vs baseline: 1.3397x; 1.2076x over previous
//
#include <hip/hip_runtime.h>
#include <hip/hip_bf16.h>
#include <math.h>

#define B_ 4
#define L_ 2048
#define D_ 2048
#define M_ 64
#define R_ 128
#define NTOK (B_*L_)
#define SCALE_ 0.125f
#define C_ 32
#define NCH (L_/C_)

typedef __attribute__((ext_vector_type(8))) short short8;
typedef __attribute__((ext_vector_type(4))) float f32x4;

// lgkmcnt-only barrier: LDS visibility without draining vmcnt, so global
// prefetch loads stay in flight across chunk phases (counted-vmcnt principle).
#define BAR() asm volatile("s_waitcnt lgkmcnt(0)\n\ts_barrier" ::: "memory")

#define MFMA(a, b, c) __builtin_amdgcn_mfma_f32_16x16x32_bf16((a), (b), (c), 0, 0, 0)

__device__ __forceinline__ unsigned short f2bfu(float v) {
    union { float f; unsigned u; } a; a.f = v;
    unsigned r = a.u + 0x7fffu + ((a.u >> 16) & 1u);
    return (unsigned short)(r >> 16);
}
__device__ __forceinline__ float bfu2f(unsigned short h) {
    union { unsigned u; float f; } a; a.u = ((unsigned)h) << 16;
    return a.f;
}

// ---------------- 1. causal depthwise conv (W=4) + silu, float4 ----------
__global__ __launch_bounds__(256) void k_conv(const float* __restrict__ x,
    const float* __restrict__ cw, const float* __restrict__ cb,
    float* __restrict__ shift)
{
    size_t i4 = (size_t)blockIdx.x * 256 + threadIdx.x;   // float4 index
    int dq = (int)(i4 % (D_ / 4));
    size_t n = i4 / (D_ / 4);
    int l = (int)(n % L_);
    int d0 = dq * 4;
    const float* xb = x + n * D_ + d0;
    float4 w0 = *(const float4*)(cw + (size_t)d0 * 4);
    float4 w1 = *(const float4*)(cw + (size_t)(d0 + 1) * 4);
    float4 w2 = *(const float4*)(cw + (size_t)(d0 + 2) * 4);
    float4 w3 = *(const float4*)(cw + (size_t)(d0 + 3) * 4);
    float4 acc = *(const float4*)(cb + d0);
#pragma unroll
    for (int i = 0; i < 4; i++) {
        if (l - 3 + i >= 0) {
            float4 xv = *(const float4*)(xb + (size_t)(i - 3) * D_);
            acc.x = fmaf(xv.x, ((const float*)&w0)[i], acc.x);
            acc.y = fmaf(xv.y, ((const float*)&w1)[i], acc.y);
            acc.z = fmaf(xv.z, ((const float*)&w2)[i], acc.z);
            acc.w = fmaf(xv.w, ((const float*)&w3)[i], acc.w);
        }
    }
    float4 o;
    o.x = acc.x / (1.f + expf(-acc.x));
    o.y = acc.y / (1.f + expf(-acc.y));
    o.z = acc.z / (1.f + expf(-acc.z));
    o.w = acc.w / (1.f + expf(-acc.w));
    *(float4*)(shift + n * D_ + d0) = o;
}

// ---------------- weight cast fp32 -> bf16 ----------------
__device__ __forceinline__ unsigned pkbf(float a, float b) {
    union { __hip_bfloat162 h; unsigned u; } cv;
    cv.h = __float22bfloat162_rn(make_float2(a, b));
    return cv.u;
}

__global__ __launch_bounds__(256) void k_castw(
    const float* __restrict__ s0, const float* __restrict__ s1,
    const float* __restrict__ s2, const float* __restrict__ s3,
    unsigned short* __restrict__ d0, unsigned short* __restrict__ d1,
    unsigned short* __restrict__ d2, unsigned short* __restrict__ d3)
{
    int which = blockIdx.x >> 8;
    int idx = ((blockIdx.x & 255) * 256 + threadIdx.x) * 4;
    const float* s = which == 0 ? s0 : which == 1 ? s1 : which == 2 ? s2 : s3;
    unsigned short* d = which == 0 ? d0 : which == 1 ? d1 : which == 2 ? d2 : d3;
    float4 v = *(const float4*)(s + idx);
    uint2 o;
    o.x = pkbf(v.x, v.y);
    o.y = pkbf(v.z, v.w);
    *(uint2*)(d + idx) = o;
}

// ---------------- bf16 MFMA NT GEMM (unchanged) ----------------
__global__ __launch_bounds__(256) void k_mfma_nt(
    const float* __restrict__ A, const unsigned short* __restrict__ Bb,
    float* __restrict__ out, int K, int ldo, int jo,
    int mode, const float* __restrict__ bias, const float* __restrict__ xmul)
{
    __shared__ unsigned short As[128 * 32];
    __shared__ unsigned short Bs[128 * 32];
    int tid = threadIdx.x;
    int n0 = blockIdx.x * 128;
    int jblk = blockIdx.y * 128;
    int wave = tid >> 6, lane = tid & 63;
    int quad = lane >> 4, lcol = lane & 15;
    int wrow = (wave >> 1) * 64, wcol = (wave & 1) * 64;

    f32x4 acc[4][4];
#pragma unroll
    for (int i = 0; i < 4; i++)
#pragma unroll
        for (int j = 0; j < 4; j++) acc[i][j] = {0.f, 0.f, 0.f, 0.f};

    for (int k0 = 0; k0 < K; k0 += 32) {
        float4 a0[2][2];
        uint4 bv[2];
#pragma unroll
        for (int p = 0; p < 2; p++) {
            int idx = p * 256 + tid;
            int row = idx >> 2, sub = idx & 3;
            const float* ap = A + (size_t)(n0 + row) * K + k0 + sub * 8;
            a0[p][0] = *(const float4*)ap;
            a0[p][1] = *(const float4*)(ap + 4);
            bv[p] = *(const uint4*)(Bb + (size_t)(jblk + row) * K + k0 + sub * 8);
        }
        __syncthreads();
#pragma unroll
        for (int p = 0; p < 2; p++) {
            int idx = p * 256 + tid;
            int row = idx >> 2, sub = idx & 3;
            uint4 w;
            w.x = pkbf(a0[p][0].x, a0[p][0].y);
            w.y = pkbf(a0[p][0].z, a0[p][0].w);
            w.z = pkbf(a0[p][1].x, a0[p][1].y);
            w.w = pkbf(a0[p][1].z, a0[p][1].w);
            *(uint4*)&As[row * 32 + sub * 8] = w;
            *(uint4*)&Bs[row * 32 + sub * 8] = bv[p];
        }
        __syncthreads();
        short8 af[4], bfr[4];
#pragma unroll
        for (int i = 0; i < 4; i++)
            af[i] = *(short8*)&As[(wrow + i * 16 + lcol) * 32 + quad * 8];
#pragma unroll
        for (int j = 0; j < 4; j++)
            bfr[j] = *(short8*)&Bs[(wcol + j * 16 + lcol) * 32 + quad * 8];
#pragma unroll
        for (int i = 0; i < 4; i++)
#pragma unroll
            for (int j = 0; j < 4; j++)
                acc[i][j] = __builtin_amdgcn_mfma_f32_16x16x32_bf16(
                    af[i], bfr[j], acc[i][j], 0, 0, 0);
    }

#pragma unroll
    for (int i = 0; i < 4; i++) {
#pragma unroll
        for (int j = 0; j < 4; j++) {
#pragma unroll
            for (int q = 0; q < 4; q++) {
                int row = wrow + i * 16 + quad * 4 + q;
                int col = wcol + j * 16 + lcol;
                int n = n0 + row;
                int jc = jblk + col;
                float val = acc[i][j][q];
                if (mode == 1) {
                    val += bias[jc];
                    val = 1.f / (1.f + expf(-val));
                    val *= xmul[(size_t)n * ldo + jo + jc];
                }
                out[(size_t)n * ldo + jo + jc] = val;
            }
        }
    }
}

// ---------------- 5. per-chunk gate prep (C=32) ----------------
// One block per (batch, chunk): 4 groups x 64 m, each group 8 tokens.
// Emits bf16 rt = r*e^lam, kd = k*e^-lam (token-major [t][64]) and
// kc = k*e^(tot-lam) (m-major [m][32]) + f32 aC = e^tot.
__global__ __launch_bounds__(256) void k_prep(const float* __restrict__ rkmg,
    const float* __restrict__ mb,
    unsigned short* __restrict__ Rt, unsigned short* __restrict__ Kd,
    unsigned short* __restrict__ Kc, float* __restrict__ Ac)
{
    __shared__ float seg[4 * 64];
    int blk = blockIdx.x;                 // b*NCH + chunk
    int sg = threadIdx.x >> 6, mm = threadIdx.x & 63;
    int n0 = blk * C_ + sg * 8;

    float rr[8], kk[8], lamr[8];
    float csum = 0.f;
#pragma unroll
    for (int j = 0; j < 8; j++) {
        const float* row = rkmg + (size_t)(n0 + j) * 256;
        float r   = row[mm];
        float k   = row[64 + mm];
        float mg1 = row[128 + mm] + mb[mm];
        float mg2 = row[192 + mm] + mb[64 + mm];
        float sel = (mg1 > 20.f) ? mg1 : log1pf(expf(mg1));
        float tau = 1.f / (1.f + expf(-mg2));
        float it  = expf(tau * logf(sel));
        float g   = -sel * tau;
        float s2  = k * k;
#pragma unroll
        for (int off = 32; off >= 1; off >>= 1) s2 += __shfl_xor(s2, off, 64);
        float kn = k / fmaxf(sqrtf(s2), 1e-12f);
        rr[j] = r;
        kk[j] = kn * it;
        csum += g;
        lamr[j] = csum;                  // inclusive cumsum within group
    }
    seg[sg * 64 + mm] = csum;
    __syncthreads();
    float off = 0.f, tot = 0.f;
#pragma unroll
    for (int s = 0; s < 4; s++) {
        float v = seg[s * 64 + mm];
        if (s < sg) off += v;
        tot += v;
    }
    size_t obase = (size_t)blk * (C_ * 64);
    unsigned short kcp[8];
#pragma unroll
    for (int j = 0; j < 8; j++) {
        float lam = off + lamr[j];
        Rt[obase + (size_t)(sg * 8 + j) * 64 + mm] = f2bfu(rr[j] * expf(lam));
        Kd[obase + (size_t)(sg * 8 + j) * 64 + mm] = f2bfu(kk[j] * expf(-lam));
        kcp[j] = f2bfu(kk[j] * expf(tot - lam));
    }
    ushort4 ka4, kb4;
    ka4.x = kcp[0]; ka4.y = kcp[1]; ka4.z = kcp[2]; ka4.w = kcp[3];
    kb4.x = kcp[4]; kb4.y = kcp[5]; kb4.z = kcp[6]; kb4.w = kcp[7];
    *(ushort4*)&Kc[obase + (size_t)mm * C_ + sg * 8]     = ka4;
    *(ushort4*)&Kc[obase + (size_t)mm * C_ + sg * 8 + 4] = kb4;
    if (sg == 0) Ac[(size_t)blk * 64 + mm] = expf(tot);
}

// ---------------- 6. chunked recurrence (C=32), state in f32 registers ---
// block = (b, 32-d slice): 256 blocks x 256 thr (4 waves), 1 block/CU.
// Waves 2-3 hold S (64m x 16d each) permanently in f32 accumulators:
//   sreg = aC*sreg + kc@U  (2 MFMA per 16m-tile, K=32), then one-way
//   bf16 hi/lo write to LDS ST[c&1] so O-waves can read it NEXT chunk.
// Waves 0-1 per chunk: phase1 O += rt@S_prev (8 MFMA) + wave0 P (6 MFMA);
// tail O += P@U (4 MFMA) + store. 2 raw barriers/chunk, 64 chunks.
__global__ __launch_bounds__(256) void k_chunk(
    const unsigned short* __restrict__ Rt, const unsigned short* __restrict__ Kd,
    const unsigned short* __restrict__ Kc, const float* __restrict__ Ac,
    const float* __restrict__ u, const float* __restrict__ shift,
    const float* __restrict__ rw, float* __restrict__ out)
{
    __shared__ __align__(16) unsigned short UTh[2][32 * 40]; // [d][s] dbuf
    __shared__ __align__(16) unsigned short UTl[2][32 * 40];
    __shared__ __align__(16) unsigned short rt[32 * 72];     // [t][m]
    __shared__ __align__(16) unsigned short kd[32 * 72];     // [s][m]
    __shared__ __align__(16) unsigned short kcT[64 * 40];    // [m][s]
    __shared__ __align__(16) unsigned short Pl[32 * 40];     // [t][s]
    __shared__ __align__(16) unsigned short STh[2][32 * 72]; // [d][m] pingpong
    __shared__ __align__(16) unsigned short STl[2][32 * 72];
    __shared__ __align__(16) float aCs[64];

    int tid = threadIdx.x;
    int wave = tid >> 6, lane = tid & 63;
    int quad = lane >> 4, l15 = lane & 15;
    int b = blockIdx.x & 3, slice = blockIdx.x >> 2;
    int d0 = slice * 32;

    // zero-init pads + initial state mirror (pads never rewritten; the
    // t<16,s>=16 block of Pl stays zero forever)
    for (int i = tid; i < 2 * 32 * 40; i += 256) { (&UTh[0][0])[i] = 0; (&UTl[0][0])[i] = 0; }
    for (int i = tid; i < 64 * 40; i += 256) kcT[i] = 0;
    for (int i = tid; i < 32 * 40; i += 256) Pl[i] = 0;
    for (int i = tid; i < 2 * 32 * 72; i += 256) { (&STh[0][0])[i] = 0; (&STl[0][0])[i] = 0; }

    size_t cbase = (size_t)b * (L_ * 64);
    size_t ubase = (size_t)b * L_ * D_ + d0;

    float rwv = 0.f;
    if (wave < 2) rwv = rw[d0 + wave * 16 + l15];

    // ---- prefetch chunk 0 ----
    uint4 rtv = *(const uint4*)(Rt + cbase + (size_t)tid * 8);
    uint4 kdv = *(const uint4*)(Kd + cbase + (size_t)tid * 8);
    uint4 kcv = *(const uint4*)(Kc + cbase + (size_t)tid * 8);
    float uv[4];
    {
        int dd = tid & 31, tt = tid >> 5;
#pragma unroll
        for (int j = 0; j < 4; j++) uv[j] = u[ubase + (size_t)(tt + 8 * j) * D_ + dd];
    }
    float acv = 0.f;
    if (tid < 64) acv = Ac[(size_t)b * NCH * 64 + tid];
    size_t sadr = ubase + (size_t)wave * 16 + l15 + (size_t)(quad * 4) * D_;
    float sv[8], svn[8];
#pragma unroll
    for (int q = 0; q < 8; q++) { sv[q] = 0.f; svn[q] = 0.f; }
    if (wave < 2) {
#pragma unroll
        for (int tile = 0; tile < 2; tile++)
#pragma unroll
            for (int q = 0; q < 4; q++)
                sv[tile * 4 + q] = shift[sadr + (size_t)(tile * 16 + q) * D_];
    }

    f32x4 zz = {0.f, 0.f, 0.f, 0.f};
    f32x4 sreg[4];                       // waves 2-3: S[m=mt*16+quad*4+q][d=l15]
#pragma unroll
    for (int mt = 0; mt < 4; mt++) sreg[mt] = zz;

    BAR();   // zero-init visible

    for (int c = 0; c < NCH; c++) {
        int wbuf = c & 1;          // ST written this chunk (S_c)
        int rbuf = wbuf ^ 1;       // ST read this chunk (S_{c-1})
        int ping = c & 1;          // UT buffer for this chunk

        // ---- stage chunk c ----
        {
            int t = tid >> 3, m8 = (tid & 7) * 8;
            *(uint4*)&rt[t * 72 + m8] = rtv;
            *(uint4*)&kd[t * 72 + m8] = kdv;
            int m = tid >> 2, s8 = (tid & 3) * 8;
            *(uint4*)&kcT[m * 40 + s8] = kcv;
            int dd = tid & 31, tt = tid >> 5;
#pragma unroll
            for (int j = 0; j < 4; j++) {
                unsigned short h0 = f2bfu(uv[j]);
                UTh[ping][dd * 40 + tt + 8 * j] = h0;
                UTl[ping][dd * 40 + tt + 8 * j] = f2bfu(uv[j] - bfu2f(h0));
            }
            if (tid < 64) aCs[tid] = acv;
        }

        // ---- issue prefetch for chunk c+1 (stays in flight across BARs) --
        if (c + 1 < NCH) {
            size_t g0 = cbase + (size_t)(c + 1) * 2048 + (size_t)tid * 8;
            rtv = *(const uint4*)(Rt + g0);
            kdv = *(const uint4*)(Kd + g0);
            kcv = *(const uint4*)(Kc + g0);
            size_t un = ubase + (size_t)(c + 1) * C_ * D_;
            int dd = tid & 31, tt = tid >> 5;
#pragma unroll
            for (int j = 0; j < 4; j++) uv[j] = u[un + (size_t)(tt + 8 * j) * D_ + dd];
            if (tid < 64) acv = Ac[(size_t)(b * NCH + c + 1) * 64 + tid];
            if (wave < 2) {
                size_t s0 = sadr + (size_t)(c + 1) * C_ * D_;
#pragma unroll
                for (int tile = 0; tile < 2; tile++)
#pragma unroll
                    for (int q = 0; q < 4; q++)
                        svn[tile * 4 + q] = shift[s0 + (size_t)(tile * 16 + q) * D_];
            }
        }

        BAR();   // stage visible

        // ---- phase 1 ----
        f32x4 oA0 = zz, oB0 = zz, oA1 = zz, oB1 = zz;
        if (wave < 2) {
            int h = wave;
            short8 a00 = *(const short8*)&rt[l15 * 72 + quad * 8];
            short8 a01 = *(const short8*)&rt[l15 * 72 + 32 + quad * 8];
            short8 a10 = *(const short8*)&rt[(16 + l15) * 72 + quad * 8];
            short8 a11 = *(const short8*)&rt[(16 + l15) * 72 + 32 + quad * 8];
            const unsigned short* sbh = &STh[rbuf][(h * 16 + l15) * 72];
            const unsigned short* sbl = &STl[rbuf][(h * 16 + l15) * 72];
            short8 sh0 = *(const short8*)&sbh[quad * 8];
            short8 sh1 = *(const short8*)&sbh[32 + quad * 8];
            short8 sl0 = *(const short8*)&sbl[quad * 8];
            short8 sl1 = *(const short8*)&sbl[32 + quad * 8];
            oA0 = MFMA(a00, sh0, oA0);
            oB0 = MFMA(a00, sl0, oB0);
            oA0 = MFMA(a01, sh1, oA0);
            oB0 = MFMA(a01, sl1, oB0);
            oA1 = MFMA(a10, sh0, oA1);
            oB1 = MFMA(a10, sl0, oB1);
            oA1 = MFMA(a11, sh1, oA1);
            oB1 = MFMA(a11, sl1, oB1);
            if (wave == 0) {
                short8 b00 = *(const short8*)&kd[l15 * 72 + quad * 8];
                short8 b01 = *(const short8*)&kd[l15 * 72 + 32 + quad * 8];
                short8 b10 = *(const short8*)&kd[(16 + l15) * 72 + quad * 8];
                short8 b11 = *(const short8*)&kd[(16 + l15) * 72 + 32 + quad * 8];
                f32x4 p00 = MFMA(a00, b00, zz); p00 = MFMA(a01, b01, p00);
                f32x4 p10 = MFMA(a10, b00, zz); p10 = MFMA(a11, b01, p10);
                f32x4 p11 = MFMA(a10, b10, zz); p11 = MFMA(a11, b11, p11);
#pragma unroll
                for (int q = 0; q < 4; q++) {
                    int t = quad * 4 + q;
                    Pl[t * 40 + l15]             = f2bfu((l15 <= t) ? p00[q] : 0.f);
                    Pl[(16 + t) * 40 + l15]      = f2bfu(p10[q]);
                    Pl[(16 + t) * 40 + 16 + l15] = f2bfu((l15 <= t) ? p11[q] : 0.f);
                }
            }
        } else {
            // S' = aC*S + kcT@U, state resident in sreg; one-way bf16 mirror
            int h = wave - 2;
            short8 uh = *(const short8*)&UTh[ping][(h * 16 + l15) * 40 + quad * 8];
            short8 ul = *(const short8*)&UTl[ping][(h * 16 + l15) * 40 + quad * 8];
#pragma unroll
            for (int mt = 0; mt < 4; mt++) {
                f32x4 a4 = *(const f32x4*)&aCs[mt * 16 + quad * 4];
                f32x4 s = sreg[mt];
                s[0] *= a4[0]; s[1] *= a4[1]; s[2] *= a4[2]; s[3] *= a4[3];
                short8 ka = *(const short8*)&kcT[(mt * 16 + l15) * 40 + quad * 8];
                s = MFMA(ka, uh, s);
                s = MFMA(ka, ul, s);
                sreg[mt] = s;
                int sidx = (h * 16 + l15) * 72 + mt * 16 + quad * 4;
                ushort4 nh, nl;
                unsigned short hq;
                hq = f2bfu(s[0]); nh.x = hq; nl.x = f2bfu(s[0] - bfu2f(hq));
                hq = f2bfu(s[1]); nh.y = hq; nl.y = f2bfu(s[1] - bfu2f(hq));
                hq = f2bfu(s[2]); nh.z = hq; nl.z = f2bfu(s[2] - bfu2f(hq));
                hq = f2bfu(s[3]); nh.w = hq; nl.w = f2bfu(s[3] - bfu2f(hq));
                *(ushort4*)&STh[wbuf][sidx] = nh;
                *(ushort4*)&STl[wbuf][sidx] = nl;
            }
        }

        BAR();   // Pl + ST[wbuf] visible; all phase-1 LDS reads drained

        // ---- tail: O = SCALE*(rt@S + P@U) + shift*rw ----
        if (wave < 2) {
            int h = wave;
            short8 pa0 = *(const short8*)&Pl[l15 * 40 + quad * 8];
            short8 pa1 = *(const short8*)&Pl[(16 + l15) * 40 + quad * 8];
            short8 uh = *(const short8*)&UTh[ping][(h * 16 + l15) * 40 + quad * 8];
            short8 ul = *(const short8*)&UTl[ping][(h * 16 + l15) * 40 + quad * 8];
            oA0 = MFMA(pa0, uh, oA0);
            oB0 = MFMA(pa0, ul, oB0);
            oA1 = MFMA(pa1, uh, oA1);
            oB1 = MFMA(pa1, ul, oB1);
            size_t oa = ubase + (size_t)(c * C_ + quad * 4) * D_ + h * 16 + l15;
#pragma unroll
            for (int q = 0; q < 4; q++) {
                out[oa + (size_t)q * D_]        = SCALE_ * (oA0[q] + oB0[q]) + sv[q] * rwv;
                out[oa + (size_t)(16 + q) * D_] = SCALE_ * (oA1[q] + oB1[q]) + sv[4 + q] * rwv;
            }
        }
#pragma unroll
        for (int q = 0; q < 8; q++) sv[q] = svn[q];
        // No barrier here: next stage writes rt/kd/kcT/UT[ping^1]/aCs, whose
        // phase-1 readers drained at the mid BAR; this tail reads only
        // Pl/UT[ping], and their rewriters (wave0 phase1 c+1 / stage c+2)
        // sit behind the next BAR(s).
    }
}

// ---------------- launcher ----------------
extern "C" void kernel_launch(void* const* d_in, const int* in_sizes, int n_in,
                              void* d_out, int out_size, void* d_ws, size_t ws_size,
                              hipStream_t stream)
{
    const float* x   = (const float*)d_in[0];
    const float* cw  = (const float*)d_in[1];
    const float* cb  = (const float*)d_in[2];
    const float* ipw = (const float*)d_in[3];
    const float* w0  = (const float*)d_in[4];
    const float* w1  = (const float*)d_in[5];
    const float* b1  = (const float*)d_in[6];
    const float* mw  = (const float*)d_in[7];
    const float* mb  = (const float*)d_in[8];
    const float* rw  = (const float*)d_in[9];
    float* out = (float*)d_out;

    float* ws    = (float*)d_ws;
    float* shift = ws;
    float* u     = shift + (size_t)NTOK * D_;
    float* rkmg  = u + (size_t)NTOK * D_;
    float* t1    = rkmg + (size_t)NTOK * 256;
    float* Ac    = t1 + (size_t)NTOK * R_;
    unsigned short* Rt    = (unsigned short*)(Ac + (size_t)B_ * NCH * 64);
    unsigned short* Kd    = Rt + (size_t)NTOK * 64;
    unsigned short* Kc    = Kd + (size_t)NTOK * 64;
    unsigned short* Wcatb = Kc + (size_t)NTOK * 64;
    unsigned short* w0b   = Wcatb + 256 * 2048;
    unsigned short* w1b   = w0b + 128 * 2048;

    k_conv<<<(NTOK * (size_t)D_) / 1024, 256, 0, stream>>>(x, cw, cb, shift);

    k_castw<<<1024, 256, 0, stream>>>(ipw, mw, w0, w1,
                                      Wcatb, Wcatb + 128 * 2048, w0b, w1b);

    k_mfma_nt<<<dim3(64, 2), 256, 0, stream>>>(shift, Wcatb, rkmg, D_, 256, 0,
                                               0, nullptr, nullptr);
    k_mfma_nt<<<dim3(64, 1), 256, 0, stream>>>(x, w0b, t1, D_, R_, 0,
                                               0, nullptr, nullptr);
    k_mfma_nt<<<dim3(64, 16), 256, 0, stream>>>(t1, w1b, u, R_, D_, 0,
                                                1, b1, x);

    k_prep<<<B_ * NCH, 256, 0, stream>>>(rkmg, mb, Rt, Kd, Kc, Ac);

    k_chunk<<<256, 256, 0, stream>>>(Rt, Kd, Kc, Ac, u, shift, rw, out);
}

// Round 3
// 325.530 us; speedup vs baseline: 2.0462x; 1.5273x over previous
//
#include <hip/hip_runtime.h>
#include <hip/hip_bf16.h>
#include <math.h>

#define B_ 4
#define L_ 2048
#define D_ 2048
#define M_ 64
#define R_ 128
#define NTOK (B_*L_)
#define SCALE_ 0.125f
#define C_ 32
#define NCH (L_/C_)

typedef __attribute__((ext_vector_type(8))) short short8;
typedef __attribute__((ext_vector_type(4))) float f32x4;

// lgkmcnt-only barrier: LDS visibility without draining vmcnt, so global
// prefetch loads stay in flight across phases (counted-vmcnt principle).
#define BAR() asm volatile("s_waitcnt lgkmcnt(0)\n\ts_barrier" ::: "memory")

#define MFMA(a, b, c) __builtin_amdgcn_mfma_f32_16x16x32_bf16((a), (b), (c), 0, 0, 0)

__device__ __forceinline__ unsigned short f2bfu(float v) {
    union { float f; unsigned u; } a; a.f = v;
    unsigned r = a.u + 0x7fffu + ((a.u >> 16) & 1u);
    return (unsigned short)(r >> 16);
}
__device__ __forceinline__ float bfu2f(unsigned short h) {
    union { unsigned u; float f; } a; a.u = ((unsigned)h) << 16;
    return a.f;
}
__device__ __forceinline__ unsigned pkbf(float a, float b) {
    union { __hip_bfloat162 h; unsigned u; } cv;
    cv.h = __float22bfloat162_rn(make_float2(a, b));
    return cv.u;
}

// ---------------- 1. conv (W=4) + silu; also emits bf16 x and shift -------
__global__ __launch_bounds__(256) void k_conv(const float* __restrict__ x,
    const float* __restrict__ cw, const float* __restrict__ cb,
    float* __restrict__ shift, unsigned short* __restrict__ sbf,
    unsigned short* __restrict__ xb)
{
    size_t i4 = (size_t)blockIdx.x * 256 + threadIdx.x;   // float4 index
    int dq = (int)(i4 % (D_ / 4));
    size_t n = i4 / (D_ / 4);
    int l = (int)(n % L_);
    int d0 = dq * 4;
    const float* xp = x + n * D_ + d0;
    float4 w0 = *(const float4*)(cw + (size_t)d0 * 4);
    float4 w1 = *(const float4*)(cw + (size_t)(d0 + 1) * 4);
    float4 w2 = *(const float4*)(cw + (size_t)(d0 + 2) * 4);
    float4 w3 = *(const float4*)(cw + (size_t)(d0 + 3) * 4);
    float4 acc = *(const float4*)(cb + d0);
    float4 xv3 = *(const float4*)xp;                      // tap i=3 (always valid)
#pragma unroll
    for (int i = 0; i < 3; i++) {
        if (l - 3 + i >= 0) {
            float4 xv = *(const float4*)(xp + (size_t)(i - 3) * D_);
            acc.x = fmaf(xv.x, ((const float*)&w0)[i], acc.x);
            acc.y = fmaf(xv.y, ((const float*)&w1)[i], acc.y);
            acc.z = fmaf(xv.z, ((const float*)&w2)[i], acc.z);
            acc.w = fmaf(xv.w, ((const float*)&w3)[i], acc.w);
        }
    }
    acc.x = fmaf(xv3.x, ((const float*)&w0)[3], acc.x);
    acc.y = fmaf(xv3.y, ((const float*)&w1)[3], acc.y);
    acc.z = fmaf(xv3.z, ((const float*)&w2)[3], acc.z);
    acc.w = fmaf(xv3.w, ((const float*)&w3)[3], acc.w);
    float4 o;
    o.x = acc.x / (1.f + expf(-acc.x));
    o.y = acc.y / (1.f + expf(-acc.y));
    o.z = acc.z / (1.f + expf(-acc.z));
    o.w = acc.w / (1.f + expf(-acc.w));
    *(float4*)(shift + n * D_ + d0) = o;
    uint2 sp; sp.x = pkbf(o.x, o.y); sp.y = pkbf(o.z, o.w);
    *(uint2*)(sbf + n * D_ + d0) = sp;
    uint2 xpk; xpk.x = pkbf(xv3.x, xv3.y); xpk.y = pkbf(xv3.z, xv3.w);
    *(uint2*)(xb + n * D_ + d0) = xpk;
}

// ---------------- weight cast fp32 -> bf16 ----------------
__global__ __launch_bounds__(256) void k_castw(
    const float* __restrict__ s0, const float* __restrict__ s1,
    const float* __restrict__ s2, const float* __restrict__ s3,
    unsigned short* __restrict__ d0, unsigned short* __restrict__ d1,
    unsigned short* __restrict__ d2, unsigned short* __restrict__ d3)
{
    int which = blockIdx.x >> 8;
    int idx = ((blockIdx.x & 255) * 256 + threadIdx.x) * 4;
    const float* s = which == 0 ? s0 : which == 1 ? s1 : which == 2 ? s2 : s3;
    unsigned short* d = which == 0 ? d0 : which == 1 ? d1 : which == 2 ? d2 : d3;
    float4 v = *(const float4*)(s + idx);
    uint2 o;
    o.x = pkbf(v.x, v.y);
    o.y = pkbf(v.z, v.w);
    *(uint2*)(d + idx) = o;
}

// ---------------- GEMM1+2 merged: bf16 NT, dbuf, 1 lgkm-BAR/step ---------
// grid (64, 3): y=0,1 -> rkmg = sbf @ Wcat^T (cols y*128..); y=2 -> t1b = xb @ w0^T (bf16 out)
__global__ __launch_bounds__(256) void k_gemm12(
    const unsigned short* __restrict__ sbf, const unsigned short* __restrict__ xb,
    const unsigned short* __restrict__ Wcatb, const unsigned short* __restrict__ w0b,
    float* __restrict__ rkmg, unsigned short* __restrict__ t1b)
{
    __shared__ __align__(16) unsigned short As[2][128 * 32];
    __shared__ __align__(16) unsigned short Bs[2][128 * 32];
    int tid = threadIdx.x;
    int n0 = blockIdx.x * 128;
    int y = blockIdx.y;
    const unsigned short* A = (y < 2) ? sbf : xb;
    const unsigned short* Bp = (y == 0) ? Wcatb : (y == 1) ? (Wcatb + 128 * 2048) : w0b;
    int wave = tid >> 6, lane = tid & 63;
    int quad = lane >> 4, lcol = lane & 15;
    int wrow = (wave >> 1) * 64, wcol = (wave & 1) * 64;
    int r0 = tid >> 2;
    int sub = (tid & 3) * 8;
    const unsigned short* a0p = A + (size_t)(n0 + r0) * 2048 + sub;
    const unsigned short* a1p = A + (size_t)(n0 + r0 + 64) * 2048 + sub;
    const unsigned short* b0p = Bp + (size_t)r0 * 2048 + sub;
    const unsigned short* b1p = Bp + (size_t)(r0 + 64) * 2048 + sub;

    f32x4 acc[4][4];
#pragma unroll
    for (int i = 0; i < 4; i++)
#pragma unroll
        for (int j = 0; j < 4; j++) acc[i][j] = {0.f, 0.f, 0.f, 0.f};

    uint4 av0 = *(const uint4*)a0p, av1 = *(const uint4*)a1p;
    uint4 bv0 = *(const uint4*)b0p, bv1 = *(const uint4*)b1p;
    {
        int i0 = tid * 8, i1 = 2048 + tid * 8;
        *(uint4*)&As[0][i0] = av0; *(uint4*)&As[0][i1] = av1;
        *(uint4*)&Bs[0][i0] = bv0; *(uint4*)&Bs[0][i1] = bv1;
    }
    av0 = *(const uint4*)(a0p + 32); av1 = *(const uint4*)(a1p + 32);
    bv0 = *(const uint4*)(b0p + 32); bv1 = *(const uint4*)(b1p + 32);
    BAR();

    for (int k32 = 0; k32 < 64; k32++) {
        int cur = k32 & 1;
        short8 af[4], bfr[4];
#pragma unroll
        for (int i = 0; i < 4; i++)
            af[i] = *(short8*)&As[cur][(wrow + i * 16 + lcol) * 32 + quad * 8];
#pragma unroll
        for (int j = 0; j < 4; j++)
            bfr[j] = *(short8*)&Bs[cur][(wcol + j * 16 + lcol) * 32 + quad * 8];
#pragma unroll
        for (int i = 0; i < 4; i++)
#pragma unroll
            for (int j = 0; j < 4; j++)
                acc[i][j] = MFMA(af[i], bfr[j], acc[i][j]);
        if (k32 + 1 < 64) {
            int nb = cur ^ 1;
            int i0 = tid * 8, i1 = 2048 + tid * 8;
            *(uint4*)&As[nb][i0] = av0; *(uint4*)&As[nb][i1] = av1;
            *(uint4*)&Bs[nb][i0] = bv0; *(uint4*)&Bs[nb][i1] = bv1;
        }
        if (k32 + 2 < 64) {
            int k0 = (k32 + 2) * 32;
            av0 = *(const uint4*)(a0p + k0); av1 = *(const uint4*)(a1p + k0);
            bv0 = *(const uint4*)(b0p + k0); bv1 = *(const uint4*)(b1p + k0);
        }
        BAR();
    }

#pragma unroll
    for (int i = 0; i < 4; i++)
#pragma unroll
        for (int j = 0; j < 4; j++)
#pragma unroll
            for (int q = 0; q < 4; q++) {
                int row = wrow + i * 16 + quad * 4 + q;
                int col = wcol + j * 16 + lcol;
                int n = n0 + row;
                if (y < 2) rkmg[(size_t)n * 256 + y * 128 + col] = acc[i][j][q];
                else       t1b[(size_t)n * 128 + col] = f2bfu(acc[i][j][q]);
            }
}

// ---------------- GEMM3: u = sigmoid(t1b @ w1^T + b1) * x --------------
__global__ __launch_bounds__(256) void k_gemm3(
    const unsigned short* __restrict__ t1b, const unsigned short* __restrict__ w1b,
    const float* __restrict__ b1, const float* __restrict__ x,
    float* __restrict__ u)
{
    __shared__ __align__(16) unsigned short As[2][128 * 32];
    __shared__ __align__(16) unsigned short Bs[2][128 * 32];
    int tid = threadIdx.x;
    int n0 = blockIdx.x * 128;
    int jblk = blockIdx.y * 128;
    int wave = tid >> 6, lane = tid & 63;
    int quad = lane >> 4, lcol = lane & 15;
    int wrow = (wave >> 1) * 64, wcol = (wave & 1) * 64;
    int r0 = tid >> 2;
    int sub = (tid & 3) * 8;
    const unsigned short* a0p = t1b + (size_t)(n0 + r0) * 128 + sub;
    const unsigned short* a1p = t1b + (size_t)(n0 + r0 + 64) * 128 + sub;
    const unsigned short* b0p = w1b + (size_t)(jblk + r0) * 128 + sub;
    const unsigned short* b1p = w1b + (size_t)(jblk + r0 + 64) * 128 + sub;

    f32x4 acc[4][4];
#pragma unroll
    for (int i = 0; i < 4; i++)
#pragma unroll
        for (int j = 0; j < 4; j++) acc[i][j] = {0.f, 0.f, 0.f, 0.f};

    uint4 av0 = *(const uint4*)a0p, av1 = *(const uint4*)a1p;
    uint4 bv0 = *(const uint4*)b0p, bv1 = *(const uint4*)b1p;
    {
        int i0 = tid * 8, i1 = 2048 + tid * 8;
        *(uint4*)&As[0][i0] = av0; *(uint4*)&As[0][i1] = av1;
        *(uint4*)&Bs[0][i0] = bv0; *(uint4*)&Bs[0][i1] = bv1;
    }
    av0 = *(const uint4*)(a0p + 32); av1 = *(const uint4*)(a1p + 32);
    bv0 = *(const uint4*)(b0p + 32); bv1 = *(const uint4*)(b1p + 32);
    BAR();

    for (int k32 = 0; k32 < 4; k32++) {
        int cur = k32 & 1;
        short8 af[4], bfr[4];
#pragma unroll
        for (int i = 0; i < 4; i++)
            af[i] = *(short8*)&As[cur][(wrow + i * 16 + lcol) * 32 + quad * 8];
#pragma unroll
        for (int j = 0; j < 4; j++)
            bfr[j] = *(short8*)&Bs[cur][(wcol + j * 16 + lcol) * 32 + quad * 8];
#pragma unroll
        for (int i = 0; i < 4; i++)
#pragma unroll
            for (int j = 0; j < 4; j++)
                acc[i][j] = MFMA(af[i], bfr[j], acc[i][j]);
        if (k32 + 1 < 4) {
            int nb = cur ^ 1;
            int i0 = tid * 8, i1 = 2048 + tid * 8;
            *(uint4*)&As[nb][i0] = av0; *(uint4*)&As[nb][i1] = av1;
            *(uint4*)&Bs[nb][i0] = bv0; *(uint4*)&Bs[nb][i1] = bv1;
        }
        if (k32 + 2 < 4) {
            int k0 = (k32 + 2) * 32;
            av0 = *(const uint4*)(a0p + k0); av1 = *(const uint4*)(a1p + k0);
            bv0 = *(const uint4*)(b0p + k0); bv1 = *(const uint4*)(b1p + k0);
        }
        BAR();
    }

#pragma unroll
    for (int i = 0; i < 4; i++)
#pragma unroll
        for (int j = 0; j < 4; j++)
#pragma unroll
            for (int q = 0; q < 4; q++) {
                int row = wrow + i * 16 + quad * 4 + q;
                int col = wcol + j * 16 + lcol;
                int n = n0 + row, jc = jblk + col;
                float val = acc[i][j][q] + b1[jc];
                val = 1.f / (1.f + expf(-val));
                val *= x[(size_t)n * D_ + jc];
                u[(size_t)n * D_ + jc] = val;
            }
}

// ---------------- gate prep (C=32) + precomputed P ------------------------
// One block per (batch, chunk). Emits bf16 rt/kc + f32 aC AND the intra-chunk
// P = mask(rt @ kd^T) (32x32 bf16) so k_chunk needs no mid-chunk barrier.
__global__ __launch_bounds__(256) void k_prep(const float* __restrict__ rkmg,
    const float* __restrict__ mb,
    unsigned short* __restrict__ Rt, unsigned short* __restrict__ Kc,
    float* __restrict__ Ac, unsigned short* __restrict__ Pg)
{
    __shared__ float seg[4 * 64];
    __shared__ __align__(16) unsigned short rtL[32 * 72];
    __shared__ __align__(16) unsigned short kdL[32 * 72];
    int blk = blockIdx.x;                 // b*NCH + chunk
    int sg = threadIdx.x >> 6, mm = threadIdx.x & 63;
    int n0 = blk * C_ + sg * 8;

    float rr[8], kk[8], lamr[8];
    float csum = 0.f;
#pragma unroll
    for (int j = 0; j < 8; j++) {
        const float* row = rkmg + (size_t)(n0 + j) * 256;
        float r   = row[mm];
        float k   = row[64 + mm];
        float mg1 = row[128 + mm] + mb[mm];
        float mg2 = row[192 + mm] + mb[64 + mm];
        float sel = (mg1 > 20.f) ? mg1 : log1pf(expf(mg1));
        float tau = 1.f / (1.f + expf(-mg2));
        float it  = expf(tau * logf(sel));
        float g   = -sel * tau;
        float s2  = k * k;
#pragma unroll
        for (int off = 32; off >= 1; off >>= 1) s2 += __shfl_xor(s2, off, 64);
        float kn = k / fmaxf(sqrtf(s2), 1e-12f);
        rr[j] = r;
        kk[j] = kn * it;
        csum += g;
        lamr[j] = csum;
    }
    seg[sg * 64 + mm] = csum;
    __syncthreads();
    float off = 0.f, tot = 0.f;
#pragma unroll
    for (int s = 0; s < 4; s++) {
        float v = seg[s * 64 + mm];
        if (s < sg) off += v;
        tot += v;
    }
    size_t obase = (size_t)blk * (C_ * 64);
    unsigned short kcp[8];
#pragma unroll
    for (int j = 0; j < 8; j++) {
        float lam = off + lamr[j];
        unsigned short rv = f2bfu(rr[j] * expf(lam));
        unsigned short kv = f2bfu(kk[j] * expf(-lam));
        int t = sg * 8 + j;
        Rt[obase + (size_t)t * 64 + mm] = rv;
        rtL[t * 72 + mm] = rv;
        kdL[t * 72 + mm] = kv;
        kcp[j] = f2bfu(kk[j] * expf(tot - lam));
    }
    ushort4 ka4, kb4;
    ka4.x = kcp[0]; ka4.y = kcp[1]; ka4.z = kcp[2]; ka4.w = kcp[3];
    kb4.x = kcp[4]; kb4.y = kcp[5]; kb4.z = kcp[6]; kb4.w = kcp[7];
    *(ushort4*)&Kc[obase + (size_t)mm * C_ + sg * 8]     = ka4;
    *(ushort4*)&Kc[obase + (size_t)mm * C_ + sg * 8 + 4] = kb4;
    if (sg == 0) Ac[(size_t)blk * 64 + mm] = expf(tot);
    __syncthreads();

    // P tiles: sg0 -> (t<16,s<16); sg1 -> (t>=16,s<16); sg2 -> (t>=16,s>=16);
    // sg3 zeroes the (t<16,s>=16) block.
    int lane = threadIdx.x & 63, quad = lane >> 4, l15 = lane & 15;
    size_t pb = (size_t)blk * 1024;
    if (sg < 3) {
        int ti = (sg == 0) ? 0 : 16;
        int si = (sg == 2) ? 16 : 0;
        short8 a0 = *(const short8*)&rtL[(ti + l15) * 72 + quad * 8];
        short8 a1 = *(const short8*)&rtL[(ti + l15) * 72 + 32 + quad * 8];
        short8 b0 = *(const short8*)&kdL[(si + l15) * 72 + quad * 8];
        short8 b1 = *(const short8*)&kdL[(si + l15) * 72 + 32 + quad * 8];
        f32x4 pp = {0.f, 0.f, 0.f, 0.f};
        pp = MFMA(a0, b0, pp);
        pp = MFMA(a1, b1, pp);
#pragma unroll
        for (int q = 0; q < 4; q++) {
            int t = ti + quad * 4 + q, s = si + l15;
            Pg[pb + t * 32 + s] = f2bfu((s <= t) ? pp[q] : 0.f);
        }
    } else {
#pragma unroll
        for (int q = 0; q < 4; q++)
            Pg[pb + (quad * 4 + q) * 32 + 16 + l15] = 0;
    }
}

// ---------------- chunked recurrence: 1 barrier/chunk --------------------
// block = (b, 32-d slice): 256 blocks x 4 waves. Per chunk: stage(c+1) ||
// compute(c): O-waves (0,1): O = rt@S_prev + P@U (12 MFMA) + store;
// S-waves (2,3): sreg = aC*sreg + kc@U (8 MFMA) + bf16 hi/lo mirror to ST.
// All staged arrays double-buffered; 2-deep global prefetch; ONE BAR/chunk.
#define STAGE(q) do { \
    int t_ = tid >> 3, m8_ = (tid & 7) * 8; \
    *(uint4*)&rtS[q][t_ * 72 + m8_] = rtv; \
    int m_ = tid >> 2, s8_ = (tid & 3) * 8; \
    *(uint4*)&kcS[q][m_ * 40 + s8_] = kcv; \
    int s4_ = (tid & 7) * 4; \
    *(ushort4*)&PlS[q][t_ * 40 + s4_] = plv; \
    int dd_ = tid & 31, tt_ = tid >> 5; \
    _Pragma("unroll") \
    for (int j_ = 0; j_ < 4; j_++) { \
        unsigned short h_ = f2bfu(uv[j_]); \
        UTh[q][dd_ * 40 + tt_ + 8 * j_] = h_; \
        UTl[q][dd_ * 40 + tt_ + 8 * j_] = f2bfu(uv[j_] - bfu2f(h_)); \
    } \
    if (tid < 64) aCs[q][tid] = acv; \
} while (0)

#define PREFETCH(n) do { \
    size_t g_ = cbase + (size_t)(n) * 2048 + (size_t)tid * 8; \
    rtv = *(const uint4*)(Rt + g_); \
    kcv = *(const uint4*)(Kc + g_); \
    plv = *(const ushort4*)(Pg + pbase + (size_t)(n) * 1024 + tid * 4); \
    size_t un_ = ubase + (size_t)(n) * C_ * D_; \
    int dd_ = tid & 31, tt_ = tid >> 5; \
    _Pragma("unroll") \
    for (int j_ = 0; j_ < 4; j_++) \
        uv[j_] = u[un_ + (size_t)(tt_ + 8 * j_) * D_ + dd_]; \
    if (tid < 64) acv = Ac[(size_t)(bNCH + (n)) * 64 + tid]; \
} while (0)

__global__ __launch_bounds__(256) void k_chunk(
    const unsigned short* __restrict__ Rt, const unsigned short* __restrict__ Kc,
    const float* __restrict__ Ac, const unsigned short* __restrict__ Pg,
    const float* __restrict__ u, const float* __restrict__ shift,
    const float* __restrict__ rw, float* __restrict__ out)
{
    __shared__ __align__(16) unsigned short rtS[2][32 * 72];   // [t][m]
    __shared__ __align__(16) unsigned short PlS[2][32 * 40];   // [t][s]
    __shared__ __align__(16) unsigned short kcS[2][64 * 40];   // [m][s]
    __shared__ __align__(16) unsigned short UTh[2][32 * 40];   // [d][s]
    __shared__ __align__(16) unsigned short UTl[2][32 * 40];
    __shared__ __align__(16) unsigned short STh[2][32 * 72];   // [d][m]
    __shared__ __align__(16) unsigned short STl[2][32 * 72];
    __shared__ float aCs[2][64];

    int tid = threadIdx.x;
    int wave = tid >> 6, lane = tid & 63;
    int quad = lane >> 4, l15 = lane & 15;
    int b = blockIdx.x & 3, slice = blockIdx.x >> 2;
    int d0 = slice * 32;
    int bNCH = b * NCH;

    // zero initial state (S_{-1} = 0); other pads are never read
    for (int i = tid; i < 2 * 32 * 72; i += 256) {
        (&STh[0][0])[i] = 0; (&STl[0][0])[i] = 0;
    }

    size_t cbase = (size_t)b * (L_ * 64);
    size_t pbase = (size_t)bNCH * 1024;
    size_t ubase = (size_t)b * L_ * D_ + d0;

    float rwv = (wave < 2) ? rw[d0 + wave * 16 + l15] : 0.f;

    uint4 rtv, kcv;
    ushort4 plv;
    float uv[4], acv = 0.f;
    float sv[8], svn[8];
    size_t sadr = ubase + (size_t)wave * 16 + l15 + (size_t)(quad * 4) * D_;

    PREFETCH(0);
    STAGE(0);
    PREFETCH(1);
    if (wave < 2) {
#pragma unroll
        for (int tile = 0; tile < 2; tile++)
#pragma unroll
            for (int q = 0; q < 4; q++)
                sv[tile * 4 + q] = shift[sadr + (size_t)(tile * 16 + q) * D_];
    }
    BAR();   // zero-init + stage(0) visible

    f32x4 zz = {0.f, 0.f, 0.f, 0.f};
    f32x4 sreg[4];
#pragma unroll
    for (int mt = 0; mt < 4; mt++) sreg[mt] = zz;

    for (int c = 0; c < NCH; c++) {
        int p = c & 1;
        if (c + 1 < NCH) STAGE(p ^ 1);
        if (c + 2 < NCH) PREFETCH(c + 2);

        if (wave < 2) {
            // ---- O-waves ----
            if (c + 1 < NCH) {
                size_t s0_ = sadr + (size_t)(c + 1) * C_ * D_;
#pragma unroll
                for (int tile = 0; tile < 2; tile++)
#pragma unroll
                    for (int q = 0; q < 4; q++)
                        svn[tile * 4 + q] = shift[s0_ + (size_t)(tile * 16 + q) * D_];
            }
            int h = wave;
            short8 a00 = *(const short8*)&rtS[p][l15 * 72 + quad * 8];
            short8 a01 = *(const short8*)&rtS[p][l15 * 72 + 32 + quad * 8];
            short8 a10 = *(const short8*)&rtS[p][(16 + l15) * 72 + quad * 8];
            short8 a11 = *(const short8*)&rtS[p][(16 + l15) * 72 + 32 + quad * 8];
            const unsigned short* sbh = &STh[p ^ 1][(h * 16 + l15) * 72];
            const unsigned short* sbl = &STl[p ^ 1][(h * 16 + l15) * 72];
            short8 sh0 = *(const short8*)&sbh[quad * 8];
            short8 sh1 = *(const short8*)&sbh[32 + quad * 8];
            short8 sl0 = *(const short8*)&sbl[quad * 8];
            short8 sl1 = *(const short8*)&sbl[32 + quad * 8];
            short8 pa0 = *(const short8*)&PlS[p][l15 * 40 + quad * 8];
            short8 pa1 = *(const short8*)&PlS[p][(16 + l15) * 40 + quad * 8];
            short8 uh = *(const short8*)&UTh[p][(h * 16 + l15) * 40 + quad * 8];
            short8 ul = *(const short8*)&UTl[p][(h * 16 + l15) * 40 + quad * 8];
            __builtin_amdgcn_s_setprio(1);
            f32x4 oA0 = MFMA(a00, sh0, zz); oA0 = MFMA(a01, sh1, oA0); oA0 = MFMA(pa0, uh, oA0);
            f32x4 oB0 = MFMA(a00, sl0, zz); oB0 = MFMA(a01, sl1, oB0); oB0 = MFMA(pa0, ul, oB0);
            f32x4 oA1 = MFMA(a10, sh0, zz); oA1 = MFMA(a11, sh1, oA1); oA1 = MFMA(pa1, uh, oA1);
            f32x4 oB1 = MFMA(a10, sl0, zz); oB1 = MFMA(a11, sl1, oB1); oB1 = MFMA(pa1, ul, oB1);
            __builtin_amdgcn_s_setprio(0);
            size_t oa = ubase + (size_t)(c * C_ + quad * 4) * D_ + h * 16 + l15;
#pragma unroll
            for (int q = 0; q < 4; q++) {
                out[oa + (size_t)q * D_]        = SCALE_ * (oA0[q] + oB0[q]) + sv[q] * rwv;
                out[oa + (size_t)(16 + q) * D_] = SCALE_ * (oA1[q] + oB1[q]) + sv[4 + q] * rwv;
            }
#pragma unroll
            for (int q = 0; q < 8; q++) sv[q] = svn[q];
        } else {
            // ---- S-waves: sreg = aC*sreg + kc@U; bf16 hi/lo mirror -> ST[p]
            int h = wave - 2;
            short8 uh = *(const short8*)&UTh[p][(h * 16 + l15) * 40 + quad * 8];
            short8 ul = *(const short8*)&UTl[p][(h * 16 + l15) * 40 + quad * 8];
            __builtin_amdgcn_s_setprio(1);
#pragma unroll
            for (int mt = 0; mt < 4; mt++) {
                f32x4 a4 = *(const f32x4*)&aCs[p][mt * 16 + quad * 4];
                f32x4 s = sreg[mt];
                s[0] *= a4[0]; s[1] *= a4[1]; s[2] *= a4[2]; s[3] *= a4[3];
                short8 ka = *(const short8*)&kcS[p][(mt * 16 + l15) * 40 + quad * 8];
                s = MFMA(ka, uh, s);
                s = MFMA(ka, ul, s);
                sreg[mt] = s;
                unsigned hA = pkbf(s[0], s[1]);
                unsigned hB = pkbf(s[2], s[3]);
                float f0 = bfu2f((unsigned short)hA), f1 = bfu2f((unsigned short)(hA >> 16));
                float f2 = bfu2f((unsigned short)hB), f3 = bfu2f((unsigned short)(hB >> 16));
                unsigned lA = pkbf(s[0] - f0, s[1] - f1);
                unsigned lB = pkbf(s[2] - f2, s[3] - f3);
                int sidx = (h * 16 + l15) * 72 + mt * 16 + quad * 4;
                uint2 wh; wh.x = hA; wh.y = hB;
                uint2 wl; wl.x = lA; wl.y = lB;
                *(uint2*)&STh[p][sidx] = wh;
                *(uint2*)&STl[p][sidx] = wl;
            }
            __builtin_amdgcn_s_setprio(0);
        }
        BAR();   // stage(c+1) + ST[p] + Pl/UT reads all settled
    }
}

// ---------------- launcher ----------------
extern "C" void kernel_launch(void* const* d_in, const int* in_sizes, int n_in,
                              void* d_out, int out_size, void* d_ws, size_t ws_size,
                              hipStream_t stream)
{
    const float* x   = (const float*)d_in[0];
    const float* cw  = (const float*)d_in[1];
    const float* cb  = (const float*)d_in[2];
    const float* ipw = (const float*)d_in[3];
    const float* w0  = (const float*)d_in[4];
    const float* w1  = (const float*)d_in[5];
    const float* b1  = (const float*)d_in[6];
    const float* mw  = (const float*)d_in[7];
    const float* mb  = (const float*)d_in[8];
    const float* rw  = (const float*)d_in[9];
    float* out = (float*)d_out;

    float* ws    = (float*)d_ws;
    float* shift = ws;                                   // NTOK*D f32
    float* u     = shift + (size_t)NTOK * D_;            // NTOK*D f32 (aliases xb+sbf)
    unsigned short* xb  = (unsigned short*)u;            // NTOK*D bf16 (dead after gemm12)
    unsigned short* sbf = xb + (size_t)NTOK * D_;        // NTOK*D bf16 (dead after gemm12)
    float* rkmg = u + (size_t)NTOK * D_;                 // NTOK*256
    float* Ac   = rkmg + (size_t)NTOK * 256;             // B*NCH*64
    unsigned short* Rt  = (unsigned short*)(Ac + (size_t)B_ * NCH * 64);
    unsigned short* Kc  = Rt + (size_t)NTOK * 64;
    unsigned short* Pg  = Kc + (size_t)NTOK * 64;        // B*NCH*1024
    unsigned short* t1b = Pg + (size_t)B_ * NCH * 1024;  // NTOK*128
    unsigned short* Wcatb = t1b + (size_t)NTOK * 128;
    unsigned short* w0b   = Wcatb + 256 * 2048;
    unsigned short* w1b   = w0b + 128 * 2048;

    k_conv<<<(NTOK * (size_t)D_) / 1024, 256, 0, stream>>>(x, cw, cb, shift, sbf, xb);

    k_castw<<<1024, 256, 0, stream>>>(ipw, mw, w0, w1,
                                      Wcatb, Wcatb + 128 * 2048, w0b, w1b);

    k_gemm12<<<dim3(64, 3), 256, 0, stream>>>(sbf, xb, Wcatb, w0b, rkmg, t1b);

    k_prep<<<B_ * NCH, 256, 0, stream>>>(rkmg, mb, Rt, Kc, Ac, Pg);

    k_gemm3<<<dim3(64, 16), 256, 0, stream>>>(t1b, w1b, b1, x, u);

    k_chunk<<<256, 256, 0, stream>>>(Rt, Kc, Ac, Pg, u, shift, rw, out);
}

// Round 4
// 284.662 us; speedup vs baseline: 2.3399x; 1.1436x over previous
//
#include <hip/hip_runtime.h>
#include <hip/hip_bf16.h>
#include <math.h>

#define B_ 4
#define L_ 2048
#define D_ 2048
#define M_ 64
#define R_ 128
#define NTOK (B_*L_)
#define SCALE_ 0.125f
#define C_ 32
#define NCH (L_/C_)

typedef __attribute__((ext_vector_type(8))) short short8;
typedef __attribute__((ext_vector_type(4))) float f32x4;

// lgkmcnt-only barrier: LDS visibility without draining vmcnt, so global
// prefetch loads stay in flight across phases (counted-vmcnt principle).
#define BAR() asm volatile("s_waitcnt lgkmcnt(0)\n\ts_barrier" ::: "memory")

#define MFMA(a, b, c) __builtin_amdgcn_mfma_f32_16x16x32_bf16((a), (b), (c), 0, 0, 0)

__device__ __forceinline__ unsigned short f2bfu(float v) {
    union { float f; unsigned u; } a; a.f = v;
    unsigned r = a.u + 0x7fffu + ((a.u >> 16) & 1u);
    return (unsigned short)(r >> 16);
}
__device__ __forceinline__ float bfu2f(unsigned short h) {
    union { unsigned u; float f; } a; a.u = ((unsigned)h) << 16;
    return a.f;
}
__device__ __forceinline__ unsigned pkbf(float a, float b) {
    union { __hip_bfloat162 h; unsigned u; } cv;
    cv.h = __float22bfloat162_rn(make_float2(a, b));
    return cv.u;
}

// ---------------- 1. conv (W=4) + silu, token-blocked (8 tok/thread) -----
// Emits shift as bf16 hi/lo pair (sh = RNE bf16, identical to old sbf) and
// bf16 x. No f32 shift stream: writes 100 MB instead of 134; x fetched ~1.1x.
__global__ __launch_bounds__(256) void k_conv(const float* __restrict__ x,
    const float* __restrict__ cw, const float* __restrict__ cb,
    unsigned short* __restrict__ sh, unsigned short* __restrict__ sl,
    unsigned short* __restrict__ xb)
{
    size_t gid = (size_t)blockIdx.x * 256 + threadIdx.x;
    int dq = (int)(gid & 511);            // D_/4 = 512 float4 per row
    size_t tg = gid >> 9;                 // token group (8 tokens)
    int d0 = dq * 4;
    size_t n0 = tg * 8;
    int l0 = (int)(n0 & (L_ - 1));
    const float* xp = x + n0 * D_ + d0;
    float4 w0 = *(const float4*)(cw + (size_t)d0 * 4);
    float4 w1 = *(const float4*)(cw + (size_t)(d0 + 1) * 4);
    float4 w2 = *(const float4*)(cw + (size_t)(d0 + 2) * 4);
    float4 w3 = *(const float4*)(cw + (size_t)(d0 + 3) * 4);
    float4 bias = *(const float4*)(cb + d0);
    float4 v[11];
    if (l0 > 0) {
        v[0] = *(const float4*)(xp - 3 * D_);
        v[1] = *(const float4*)(xp - 2 * D_);
        v[2] = *(const float4*)(xp - 1 * D_);
    } else {
        v[0] = make_float4(0.f, 0.f, 0.f, 0.f);
        v[1] = v[0]; v[2] = v[0];
    }
#pragma unroll
    for (int j = 0; j < 8; j++) v[3 + j] = *(const float4*)(xp + (size_t)j * D_);
#pragma unroll
    for (int j = 0; j < 8; j++) {
        float4 acc = bias;
#pragma unroll
        for (int i = 0; i < 4; i++) {
            float4 xv = v[j + i];
            acc.x = fmaf(xv.x, ((const float*)&w0)[i], acc.x);
            acc.y = fmaf(xv.y, ((const float*)&w1)[i], acc.y);
            acc.z = fmaf(xv.z, ((const float*)&w2)[i], acc.z);
            acc.w = fmaf(xv.w, ((const float*)&w3)[i], acc.w);
        }
        float4 o;
        o.x = acc.x / (1.f + expf(-acc.x));
        o.y = acc.y / (1.f + expf(-acc.y));
        o.z = acc.z / (1.f + expf(-acc.z));
        o.w = acc.w / (1.f + expf(-acc.w));
        ushort4 hv, lv;
        hv.x = f2bfu(o.x); lv.x = f2bfu(o.x - bfu2f(hv.x));
        hv.y = f2bfu(o.y); lv.y = f2bfu(o.y - bfu2f(hv.y));
        hv.z = f2bfu(o.z); lv.z = f2bfu(o.z - bfu2f(hv.z));
        hv.w = f2bfu(o.w); lv.w = f2bfu(o.w - bfu2f(hv.w));
        size_t oo = (n0 + j) * D_ + d0;
        *(ushort4*)(sh + oo) = hv;
        *(ushort4*)(sl + oo) = lv;
        float4 xv = v[3 + j];
        uint2 xpk; xpk.x = pkbf(xv.x, xv.y); xpk.y = pkbf(xv.z, xv.w);
        *(uint2*)(xb + oo) = xpk;
    }
}

// ---------------- weight cast fp32 -> bf16 ----------------
__global__ __launch_bounds__(256) void k_castw(
    const float* __restrict__ s0, const float* __restrict__ s1,
    const float* __restrict__ s2, const float* __restrict__ s3,
    unsigned short* __restrict__ d0, unsigned short* __restrict__ d1,
    unsigned short* __restrict__ d2, unsigned short* __restrict__ d3)
{
    int which = blockIdx.x >> 8;
    int idx = ((blockIdx.x & 255) * 256 + threadIdx.x) * 4;
    const float* s = which == 0 ? s0 : which == 1 ? s1 : which == 2 ? s2 : s3;
    unsigned short* d = which == 0 ? d0 : which == 1 ? d1 : which == 2 ? d2 : d3;
    float4 v = *(const float4*)(s + idx);
    uint2 o;
    o.x = pkbf(v.x, v.y);
    o.y = pkbf(v.z, v.w);
    *(uint2*)(d + idx) = o;
}

// ---------------- GEMM1+2 merged: 64x64 tiles, 3 blocks/CU ---------------
// grid (6, 128): x = col-panel (0..3 -> rkmg cols y*64; 4,5 -> t1b), fast
// axis so the 6 panels sharing an A-row-group are co-resident (L2-hot A).
// LDS rows padded to 72 shorts (144 B) -> ds_read_b128 spreads 8 bank groups.
__global__ __launch_bounds__(256) void k_gemm12(
    const unsigned short* __restrict__ sbf, const unsigned short* __restrict__ xb,
    const unsigned short* __restrict__ Wcatb, const unsigned short* __restrict__ w0b,
    float* __restrict__ rkmg, unsigned short* __restrict__ t1b)
{
    __shared__ __align__(16) unsigned short As[2][64 * 72];
    __shared__ __align__(16) unsigned short Bs[2][64 * 72];
    int tid = threadIdx.x;
    int y = blockIdx.x;                   // panel 0..5
    int n0 = blockIdx.y * 64;
    const unsigned short* A = (y < 4) ? sbf : xb;
    const unsigned short* Bp = (y < 4) ? (Wcatb + (size_t)y * 64 * 2048)
                                       : (w0b + (size_t)(y - 4) * 64 * 2048);
    int wave = tid >> 6, lane = tid & 63;
    int quad = lane >> 4, lcol = lane & 15;
    int wrow = (wave >> 1) * 32, wcol = (wave & 1) * 32;
    int r0 = tid >> 2, sub = (tid & 3) * 8;
    const unsigned short* ap = A + (size_t)(n0 + r0) * 2048 + sub;
    const unsigned short* bp = Bp + (size_t)r0 * 2048 + sub;
    int sidx = r0 * 72 + sub;

    f32x4 acc[2][2];
#pragma unroll
    for (int i = 0; i < 2; i++)
#pragma unroll
        for (int j = 0; j < 2; j++) acc[i][j] = {0.f, 0.f, 0.f, 0.f};

    uint4 av = *(const uint4*)ap;
    uint4 bv = *(const uint4*)bp;
    *(uint4*)&As[0][sidx] = av;
    *(uint4*)&Bs[0][sidx] = bv;
    av = *(const uint4*)(ap + 32);
    bv = *(const uint4*)(bp + 32);
    BAR();

    for (int k32 = 0; k32 < 64; k32++) {
        int cur = k32 & 1;
        short8 af[2], bfr[2];
#pragma unroll
        for (int i = 0; i < 2; i++)
            af[i] = *(short8*)&As[cur][(wrow + i * 16 + lcol) * 72 + quad * 8];
#pragma unroll
        for (int j = 0; j < 2; j++)
            bfr[j] = *(short8*)&Bs[cur][(wcol + j * 16 + lcol) * 72 + quad * 8];
#pragma unroll
        for (int i = 0; i < 2; i++)
#pragma unroll
            for (int j = 0; j < 2; j++)
                acc[i][j] = MFMA(af[i], bfr[j], acc[i][j]);
        if (k32 + 1 < 64) {
            int nb = cur ^ 1;
            *(uint4*)&As[nb][sidx] = av;
            *(uint4*)&Bs[nb][sidx] = bv;
        }
        if (k32 + 2 < 64) {
            int k0 = (k32 + 2) * 32;
            av = *(const uint4*)(ap + k0);
            bv = *(const uint4*)(bp + k0);
        }
        BAR();
    }

#pragma unroll
    for (int i = 0; i < 2; i++)
#pragma unroll
        for (int j = 0; j < 2; j++)
#pragma unroll
            for (int q = 0; q < 4; q++) {
                int row = wrow + i * 16 + quad * 4 + q;
                int col = wcol + j * 16 + lcol;
                int n = n0 + row;
                if (y < 4) rkmg[(size_t)n * 256 + y * 64 + col] = acc[i][j][q];
                else       t1b[(size_t)n * 128 + (y - 4) * 64 + col] = f2bfu(acc[i][j][q]);
            }
}

// ---------------- GEMM3: u = sigmoid(t1b @ w1^T + b1) * x --------------
__global__ __launch_bounds__(256) void k_gemm3(
    const unsigned short* __restrict__ t1b, const unsigned short* __restrict__ w1b,
    const float* __restrict__ b1, const float* __restrict__ x,
    float* __restrict__ u)
{
    __shared__ __align__(16) unsigned short As[2][128 * 32];
    __shared__ __align__(16) unsigned short Bs[2][128 * 32];
    int tid = threadIdx.x;
    int n0 = blockIdx.x * 128;
    int jblk = blockIdx.y * 128;
    int wave = tid >> 6, lane = tid & 63;
    int quad = lane >> 4, lcol = lane & 15;
    int wrow = (wave >> 1) * 64, wcol = (wave & 1) * 64;
    int r0 = tid >> 2;
    int sub = (tid & 3) * 8;
    const unsigned short* a0p = t1b + (size_t)(n0 + r0) * 128 + sub;
    const unsigned short* a1p = t1b + (size_t)(n0 + r0 + 64) * 128 + sub;
    const unsigned short* b0p = w1b + (size_t)(jblk + r0) * 128 + sub;
    const unsigned short* b1p = w1b + (size_t)(jblk + r0 + 64) * 128 + sub;

    f32x4 acc[4][4];
#pragma unroll
    for (int i = 0; i < 4; i++)
#pragma unroll
        for (int j = 0; j < 4; j++) acc[i][j] = {0.f, 0.f, 0.f, 0.f};

    uint4 av0 = *(const uint4*)a0p, av1 = *(const uint4*)a1p;
    uint4 bv0 = *(const uint4*)b0p, bv1 = *(const uint4*)b1p;
    {
        int i0 = tid * 8, i1 = 2048 + tid * 8;
        *(uint4*)&As[0][i0] = av0; *(uint4*)&As[0][i1] = av1;
        *(uint4*)&Bs[0][i0] = bv0; *(uint4*)&Bs[0][i1] = bv1;
    }
    av0 = *(const uint4*)(a0p + 32); av1 = *(const uint4*)(a1p + 32);
    bv0 = *(const uint4*)(b0p + 32); bv1 = *(const uint4*)(b1p + 32);
    BAR();

    for (int k32 = 0; k32 < 4; k32++) {
        int cur = k32 & 1;
        short8 af[4], bfr[4];
#pragma unroll
        for (int i = 0; i < 4; i++)
            af[i] = *(short8*)&As[cur][(wrow + i * 16 + lcol) * 32 + quad * 8];
#pragma unroll
        for (int j = 0; j < 4; j++)
            bfr[j] = *(short8*)&Bs[cur][(wcol + j * 16 + lcol) * 32 + quad * 8];
#pragma unroll
        for (int i = 0; i < 4; i++)
#pragma unroll
            for (int j = 0; j < 4; j++)
                acc[i][j] = MFMA(af[i], bfr[j], acc[i][j]);
        if (k32 + 1 < 4) {
            int nb = cur ^ 1;
            int i0 = tid * 8, i1 = 2048 + tid * 8;
            *(uint4*)&As[nb][i0] = av0; *(uint4*)&As[nb][i1] = av1;
            *(uint4*)&Bs[nb][i0] = bv0; *(uint4*)&Bs[nb][i1] = bv1;
        }
        if (k32 + 2 < 4) {
            int k0 = (k32 + 2) * 32;
            av0 = *(const uint4*)(a0p + k0); av1 = *(const uint4*)(a1p + k0);
            bv0 = *(const uint4*)(b0p + k0); bv1 = *(const uint4*)(b1p + k0);
        }
        BAR();
    }

#pragma unroll
    for (int i = 0; i < 4; i++)
#pragma unroll
        for (int j = 0; j < 4; j++)
#pragma unroll
            for (int q = 0; q < 4; q++) {
                int row = wrow + i * 16 + quad * 4 + q;
                int col = wcol + j * 16 + lcol;
                int n = n0 + row, jc = jblk + col;
                float val = acc[i][j][q] + b1[jc];
                val = 1.f / (1.f + expf(-val));
                val *= x[(size_t)n * D_ + jc];
                u[(size_t)n * D_ + jc] = val;
            }
}

// ---------------- gate prep (C=32) + precomputed P ------------------------
__global__ __launch_bounds__(256) void k_prep(const float* __restrict__ rkmg,
    const float* __restrict__ mb,
    unsigned short* __restrict__ Rt, unsigned short* __restrict__ Kc,
    float* __restrict__ Ac, unsigned short* __restrict__ Pg)
{
    __shared__ float seg[4 * 64];
    __shared__ __align__(16) unsigned short rtL[32 * 72];
    __shared__ __align__(16) unsigned short kdL[32 * 72];
    int blk = blockIdx.x;                 // b*NCH + chunk
    int sg = threadIdx.x >> 6, mm = threadIdx.x & 63;
    int n0 = blk * C_ + sg * 8;

    float rr[8], kk[8], lamr[8];
    float csum = 0.f;
#pragma unroll
    for (int j = 0; j < 8; j++) {
        const float* row = rkmg + (size_t)(n0 + j) * 256;
        float r   = row[mm];
        float k   = row[64 + mm];
        float mg1 = row[128 + mm] + mb[mm];
        float mg2 = row[192 + mm] + mb[64 + mm];
        float sel = (mg1 > 20.f) ? mg1 : log1pf(expf(mg1));
        float tau = 1.f / (1.f + expf(-mg2));
        float it  = expf(tau * logf(sel));
        float g   = -sel * tau;
        float s2  = k * k;
#pragma unroll
        for (int off = 32; off >= 1; off >>= 1) s2 += __shfl_xor(s2, off, 64);
        float kn = k / fmaxf(sqrtf(s2), 1e-12f);
        rr[j] = r;
        kk[j] = kn * it;
        csum += g;
        lamr[j] = csum;
    }
    seg[sg * 64 + mm] = csum;
    __syncthreads();
    float off = 0.f, tot = 0.f;
#pragma unroll
    for (int s = 0; s < 4; s++) {
        float v = seg[s * 64 + mm];
        if (s < sg) off += v;
        tot += v;
    }
    size_t obase = (size_t)blk * (C_ * 64);
    unsigned short kcp[8];
#pragma unroll
    for (int j = 0; j < 8; j++) {
        float lam = off + lamr[j];
        unsigned short rv = f2bfu(rr[j] * expf(lam));
        unsigned short kv = f2bfu(kk[j] * expf(-lam));
        int t = sg * 8 + j;
        Rt[obase + (size_t)t * 64 + mm] = rv;
        rtL[t * 72 + mm] = rv;
        kdL[t * 72 + mm] = kv;
        kcp[j] = f2bfu(kk[j] * expf(tot - lam));
    }
    ushort4 ka4, kb4;
    ka4.x = kcp[0]; ka4.y = kcp[1]; ka4.z = kcp[2]; ka4.w = kcp[3];
    kb4.x = kcp[4]; kb4.y = kcp[5]; kb4.z = kcp[6]; kb4.w = kcp[7];
    *(ushort4*)&Kc[obase + (size_t)mm * C_ + sg * 8]     = ka4;
    *(ushort4*)&Kc[obase + (size_t)mm * C_ + sg * 8 + 4] = kb4;
    if (sg == 0) Ac[(size_t)blk * 64 + mm] = expf(tot);
    __syncthreads();

    int lane = threadIdx.x & 63, quad = lane >> 4, l15 = lane & 15;
    size_t pb = (size_t)blk * 1024;
    if (sg < 3) {
        int ti = (sg == 0) ? 0 : 16;
        int si = (sg == 2) ? 16 : 0;
        short8 a0 = *(const short8*)&rtL[(ti + l15) * 72 + quad * 8];
        short8 a1 = *(const short8*)&rtL[(ti + l15) * 72 + 32 + quad * 8];
        short8 b0 = *(const short8*)&kdL[(si + l15) * 72 + quad * 8];
        short8 b1 = *(const short8*)&kdL[(si + l15) * 72 + 32 + quad * 8];
        f32x4 pp = {0.f, 0.f, 0.f, 0.f};
        pp = MFMA(a0, b0, pp);
        pp = MFMA(a1, b1, pp);
#pragma unroll
        for (int q = 0; q < 4; q++) {
            int t = ti + quad * 4 + q, s = si + l15;
            Pg[pb + t * 32 + s] = f2bfu((s <= t) ? pp[q] : 0.f);
        }
    } else {
#pragma unroll
        for (int q = 0; q < 4; q++)
            Pg[pb + (quad * 4 + q) * 32 + 16 + l15] = 0;
    }
}

// ---------------- chunked recurrence: 1 barrier/chunk --------------------
#define STAGE(q) do { \
    int t_ = tid >> 3, m8_ = (tid & 7) * 8; \
    *(uint4*)&rtS[q][t_ * 72 + m8_] = rtv; \
    int m_ = tid >> 2, s8_ = (tid & 3) * 8; \
    *(uint4*)&kcS[q][m_ * 40 + s8_] = kcv; \
    int s4_ = (tid & 7) * 4; \
    *(ushort4*)&PlS[q][t_ * 40 + s4_] = plv; \
    int dd_ = tid & 31, tt_ = tid >> 5; \
    _Pragma("unroll") \
    for (int j_ = 0; j_ < 4; j_++) { \
        unsigned short h_ = f2bfu(uv[j_]); \
        UTh[q][dd_ * 40 + tt_ + 8 * j_] = h_; \
        UTl[q][dd_ * 40 + tt_ + 8 * j_] = f2bfu(uv[j_] - bfu2f(h_)); \
    } \
    if (tid < 64) aCs[q][tid] = acv; \
} while (0)

#define PREFETCH(n) do { \
    size_t g_ = cbase + (size_t)(n) * 2048 + (size_t)tid * 8; \
    rtv = *(const uint4*)(Rt + g_); \
    kcv = *(const uint4*)(Kc + g_); \
    plv = *(const ushort4*)(Pg + pbase + (size_t)(n) * 1024 + tid * 4); \
    size_t un_ = ubase + (size_t)(n) * C_ * D_; \
    int dd_ = tid & 31, tt_ = tid >> 5; \
    _Pragma("unroll") \
    for (int j_ = 0; j_ < 4; j_++) \
        uv[j_] = u[un_ + (size_t)(tt_ + 8 * j_) * D_ + dd_]; \
    if (tid < 64) acv = Ac[(size_t)(bNCH + (n)) * 64 + tid]; \
} while (0)

__global__ __launch_bounds__(256) void k_chunk(
    const unsigned short* __restrict__ Rt, const unsigned short* __restrict__ Kc,
    const float* __restrict__ Ac, const unsigned short* __restrict__ Pg,
    const float* __restrict__ u, const unsigned short* __restrict__ sh,
    const unsigned short* __restrict__ sl,
    const float* __restrict__ rw, float* __restrict__ out)
{
    __shared__ __align__(16) unsigned short rtS[2][32 * 72];   // [t][m]
    __shared__ __align__(16) unsigned short PlS[2][32 * 40];   // [t][s]
    __shared__ __align__(16) unsigned short kcS[2][64 * 40];   // [m][s]
    __shared__ __align__(16) unsigned short UTh[2][32 * 40];   // [d][s]
    __shared__ __align__(16) unsigned short UTl[2][32 * 40];
    __shared__ __align__(16) unsigned short STh[2][32 * 72];   // [d][m]
    __shared__ __align__(16) unsigned short STl[2][32 * 72];
    __shared__ float aCs[2][64];

    int tid = threadIdx.x;
    int wave = tid >> 6, lane = tid & 63;
    int quad = lane >> 4, l15 = lane & 15;
    int b = blockIdx.x & 3, slice = blockIdx.x >> 2;
    int d0 = slice * 32;
    int bNCH = b * NCH;

    for (int i = tid; i < 2 * 32 * 72; i += 256) {
        (&STh[0][0])[i] = 0; (&STl[0][0])[i] = 0;
    }

    size_t cbase = (size_t)b * (L_ * 64);
    size_t pbase = (size_t)bNCH * 1024;
    size_t ubase = (size_t)b * L_ * D_ + d0;

    float rwv = (wave < 2) ? rw[d0 + wave * 16 + l15] : 0.f;

    uint4 rtv, kcv;
    ushort4 plv;
    float uv[4], acv = 0.f;
    unsigned short svh[8], svl[8], svhn[8], svln[8];
    size_t sadr = ubase + (size_t)wave * 16 + l15 + (size_t)(quad * 4) * D_;

    PREFETCH(0);
    STAGE(0);
    PREFETCH(1);
    if (wave < 2) {
#pragma unroll
        for (int tile = 0; tile < 2; tile++)
#pragma unroll
            for (int q = 0; q < 4; q++) {
                svh[tile * 4 + q] = sh[sadr + (size_t)(tile * 16 + q) * D_];
                svl[tile * 4 + q] = sl[sadr + (size_t)(tile * 16 + q) * D_];
            }
    }
    BAR();   // zero-init + stage(0) visible

    f32x4 zz = {0.f, 0.f, 0.f, 0.f};
    f32x4 sreg[4];
#pragma unroll
    for (int mt = 0; mt < 4; mt++) sreg[mt] = zz;

    for (int c = 0; c < NCH; c++) {
        int p = c & 1;
        if (c + 1 < NCH) STAGE(p ^ 1);
        if (c + 2 < NCH) PREFETCH(c + 2);

        if (wave < 2) {
            // ---- O-waves ----
            if (c + 1 < NCH) {
                size_t s0_ = sadr + (size_t)(c + 1) * C_ * D_;
#pragma unroll
                for (int tile = 0; tile < 2; tile++)
#pragma unroll
                    for (int q = 0; q < 4; q++) {
                        svhn[tile * 4 + q] = sh[s0_ + (size_t)(tile * 16 + q) * D_];
                        svln[tile * 4 + q] = sl[s0_ + (size_t)(tile * 16 + q) * D_];
                    }
            }
            int h = wave;
            short8 a00 = *(const short8*)&rtS[p][l15 * 72 + quad * 8];
            short8 a01 = *(const short8*)&rtS[p][l15 * 72 + 32 + quad * 8];
            short8 a10 = *(const short8*)&rtS[p][(16 + l15) * 72 + quad * 8];
            short8 a11 = *(const short8*)&rtS[p][(16 + l15) * 72 + 32 + quad * 8];
            const unsigned short* sbh = &STh[p ^ 1][(h * 16 + l15) * 72];
            const unsigned short* sbl = &STl[p ^ 1][(h * 16 + l15) * 72];
            short8 sh0 = *(const short8*)&sbh[quad * 8];
            short8 sh1 = *(const short8*)&sbh[32 + quad * 8];
            short8 sl0 = *(const short8*)&sbl[quad * 8];
            short8 sl1 = *(const short8*)&sbl[32 + quad * 8];
            short8 pa0 = *(const short8*)&PlS[p][l15 * 40 + quad * 8];
            short8 pa1 = *(const short8*)&PlS[p][(16 + l15) * 40 + quad * 8];
            short8 uh = *(const short8*)&UTh[p][(h * 16 + l15) * 40 + quad * 8];
            short8 ul = *(const short8*)&UTl[p][(h * 16 + l15) * 40 + quad * 8];
            __builtin_amdgcn_s_setprio(1);
            f32x4 oA0 = MFMA(a00, sh0, zz); oA0 = MFMA(a01, sh1, oA0); oA0 = MFMA(pa0, uh, oA0);
            f32x4 oB0 = MFMA(a00, sl0, zz); oB0 = MFMA(a01, sl1, oB0); oB0 = MFMA(pa0, ul, oB0);
            f32x4 oA1 = MFMA(a10, sh0, zz); oA1 = MFMA(a11, sh1, oA1); oA1 = MFMA(pa1, uh, oA1);
            f32x4 oB1 = MFMA(a10, sl0, zz); oB1 = MFMA(a11, sl1, oB1); oB1 = MFMA(pa1, ul, oB1);
            __builtin_amdgcn_s_setprio(0);
            size_t oa = ubase + (size_t)(c * C_ + quad * 4) * D_ + h * 16 + l15;
#pragma unroll
            for (int q = 0; q < 4; q++) {
                float r0v = bfu2f(svh[q]) + bfu2f(svl[q]);
                float r1v = bfu2f(svh[4 + q]) + bfu2f(svl[4 + q]);
                out[oa + (size_t)q * D_]        = SCALE_ * (oA0[q] + oB0[q]) + r0v * rwv;
                out[oa + (size_t)(16 + q) * D_] = SCALE_ * (oA1[q] + oB1[q]) + r1v * rwv;
            }
#pragma unroll
            for (int q = 0; q < 8; q++) { svh[q] = svhn[q]; svl[q] = svln[q]; }
        } else {
            // ---- S-waves: sreg = aC*sreg + kc@U; bf16 hi/lo mirror -> ST[p]
            int h = wave - 2;
            short8 uh = *(const short8*)&UTh[p][(h * 16 + l15) * 40 + quad * 8];
            short8 ul = *(const short8*)&UTl[p][(h * 16 + l15) * 40 + quad * 8];
            __builtin_amdgcn_s_setprio(1);
#pragma unroll
            for (int mt = 0; mt < 4; mt++) {
                f32x4 a4 = *(const f32x4*)&aCs[p][mt * 16 + quad * 4];
                f32x4 s = sreg[mt];
                s[0] *= a4[0]; s[1] *= a4[1]; s[2] *= a4[2]; s[3] *= a4[3];
                short8 ka = *(const short8*)&kcS[p][(mt * 16 + l15) * 40 + quad * 8];
                s = MFMA(ka, uh, s);
                s = MFMA(ka, ul, s);
                sreg[mt] = s;
                unsigned hA = pkbf(s[0], s[1]);
                unsigned hB = pkbf(s[2], s[3]);
                float f0 = bfu2f((unsigned short)hA), f1 = bfu2f((unsigned short)(hA >> 16));
                float f2 = bfu2f((unsigned short)hB), f3 = bfu2f((unsigned short)(hB >> 16));
                unsigned lA = pkbf(s[0] - f0, s[1] - f1);
                unsigned lB = pkbf(s[2] - f2, s[3] - f3);
                int sidx = (h * 16 + l15) * 72 + mt * 16 + quad * 4;
                uint2 wh; wh.x = hA; wh.y = hB;
                uint2 wl; wl.x = lA; wl.y = lB;
                *(uint2*)&STh[p][sidx] = wh;
                *(uint2*)&STl[p][sidx] = wl;
            }
            __builtin_amdgcn_s_setprio(0);
        }
        BAR();   // stage(c+1) + ST[p] + Pl/UT reads all settled
    }
}

// ---------------- launcher ----------------
extern "C" void kernel_launch(void* const* d_in, const int* in_sizes, int n_in,
                              void* d_out, int out_size, void* d_ws, size_t ws_size,
                              hipStream_t stream)
{
    const float* x   = (const float*)d_in[0];
    const float* cw  = (const float*)d_in[1];
    const float* cb  = (const float*)d_in[2];
    const float* ipw = (const float*)d_in[3];
    const float* w0  = (const float*)d_in[4];
    const float* w1  = (const float*)d_in[5];
    const float* b1  = (const float*)d_in[6];
    const float* mw  = (const float*)d_in[7];
    const float* mb  = (const float*)d_in[8];
    const float* rw  = (const float*)d_in[9];
    float* out = (float*)d_out;

    unsigned short* sh = (unsigned short*)d_ws;          // NTOK*D bf16 (shift hi)
    unsigned short* sl = sh + (size_t)NTOK * D_;         // NTOK*D bf16 (shift lo)
    unsigned short* xb = sl + (size_t)NTOK * D_;         // NTOK*D bf16 (dead after gemm12)
    float* u = (float*)xb;                               // NTOK*D f32, overlays xb + next
    float* rkmg = u + (size_t)NTOK * D_;                 // NTOK*256
    float* Ac   = rkmg + (size_t)NTOK * 256;             // B*NCH*64
    unsigned short* Rt  = (unsigned short*)(Ac + (size_t)B_ * NCH * 64);
    unsigned short* Kc  = Rt + (size_t)NTOK * 64;
    unsigned short* Pg  = Kc + (size_t)NTOK * 64;        // B*NCH*1024
    unsigned short* t1b = Pg + (size_t)B_ * NCH * 1024;  // NTOK*128
    unsigned short* Wcatb = t1b + (size_t)NTOK * 128;
    unsigned short* w0b   = Wcatb + 256 * 2048;
    unsigned short* w1b   = w0b + 128 * 2048;

    k_conv<<<(NTOK / 8) * (D_ / 4) / 256, 256, 0, stream>>>(x, cw, cb, sh, sl, xb);

    k_castw<<<1024, 256, 0, stream>>>(ipw, mw, w0, w1,
                                      Wcatb, Wcatb + 128 * 2048, w0b, w1b);

    k_gemm12<<<dim3(6, 128), 256, 0, stream>>>(sh, xb, Wcatb, w0b, rkmg, t1b);

    k_prep<<<B_ * NCH, 256, 0, stream>>>(rkmg, mb, Rt, Kc, Ac, Pg);

    k_gemm3<<<dim3(64, 16), 256, 0, stream>>>(t1b, w1b, b1, x, u);

    k_chunk<<<256, 256, 0, stream>>>(Rt, Kc, Ac, Pg, u, sh, sl, rw, out);
}

// Round 5
// 278.679 us; speedup vs baseline: 2.3902x; 1.0215x over previous
//
#include <hip/hip_runtime.h>
#include <hip/hip_bf16.h>
#include <math.h>

#define B_ 4
#define L_ 2048
#define D_ 2048
#define M_ 64
#define R_ 128
#define NTOK (B_*L_)
#define SCALE_ 0.125f
#define C_ 32
#define NCH (L_/C_)

typedef __attribute__((ext_vector_type(8))) short short8;
typedef __attribute__((ext_vector_type(4))) float f32x4;

// lgkmcnt-only barrier: LDS visibility without draining vmcnt, so global
// prefetch loads stay in flight across phases (counted-vmcnt principle).
#define BAR() asm volatile("s_waitcnt lgkmcnt(0)\n\ts_barrier" ::: "memory")

#define MFMA(a, b, c) __builtin_amdgcn_mfma_f32_16x16x32_bf16((a), (b), (c), 0, 0, 0)

__device__ __forceinline__ unsigned short f2bfu(float v) {
    union { float f; unsigned u; } a; a.f = v;
    unsigned r = a.u + 0x7fffu + ((a.u >> 16) & 1u);
    return (unsigned short)(r >> 16);
}
__device__ __forceinline__ float bfu2f(unsigned short h) {
    union { unsigned u; float f; } a; a.u = ((unsigned)h) << 16;
    return a.f;
}
__device__ __forceinline__ unsigned pkbf(float a, float b) {
    union { __hip_bfloat162 h; unsigned u; } cv;
    cv.h = __float22bfloat162_rn(make_float2(a, b));
    return cv.u;
}

// ---------------- 1. conv (W=4) + silu, token-blocked (8 tok/thread) -----
__global__ __launch_bounds__(256) void k_conv(const float* __restrict__ x,
    const float* __restrict__ cw, const float* __restrict__ cb,
    unsigned short* __restrict__ sh, unsigned short* __restrict__ sl,
    unsigned short* __restrict__ xb)
{
    size_t gid = (size_t)blockIdx.x * 256 + threadIdx.x;
    int dq = (int)(gid & 511);            // D_/4 = 512 float4 per row
    size_t tg = gid >> 9;                 // token group (8 tokens)
    int d0 = dq * 4;
    size_t n0 = tg * 8;
    int l0 = (int)(n0 & (L_ - 1));
    const float* xp = x + n0 * D_ + d0;
    float4 w0 = *(const float4*)(cw + (size_t)d0 * 4);
    float4 w1 = *(const float4*)(cw + (size_t)(d0 + 1) * 4);
    float4 w2 = *(const float4*)(cw + (size_t)(d0 + 2) * 4);
    float4 w3 = *(const float4*)(cw + (size_t)(d0 + 3) * 4);
    float4 bias = *(const float4*)(cb + d0);
    float4 v[11];
    if (l0 > 0) {
        v[0] = *(const float4*)(xp - 3 * D_);
        v[1] = *(const float4*)(xp - 2 * D_);
        v[2] = *(const float4*)(xp - 1 * D_);
    } else {
        v[0] = make_float4(0.f, 0.f, 0.f, 0.f);
        v[1] = v[0]; v[2] = v[0];
    }
#pragma unroll
    for (int j = 0; j < 8; j++) v[3 + j] = *(const float4*)(xp + (size_t)j * D_);
#pragma unroll
    for (int j = 0; j < 8; j++) {
        float4 acc = bias;
#pragma unroll
        for (int i = 0; i < 4; i++) {
            float4 xv = v[j + i];
            acc.x = fmaf(xv.x, ((const float*)&w0)[i], acc.x);
            acc.y = fmaf(xv.y, ((const float*)&w1)[i], acc.y);
            acc.z = fmaf(xv.z, ((const float*)&w2)[i], acc.z);
            acc.w = fmaf(xv.w, ((const float*)&w3)[i], acc.w);
        }
        float4 o;
        o.x = acc.x / (1.f + expf(-acc.x));
        o.y = acc.y / (1.f + expf(-acc.y));
        o.z = acc.z / (1.f + expf(-acc.z));
        o.w = acc.w / (1.f + expf(-acc.w));
        ushort4 hv, lv;
        hv.x = f2bfu(o.x); lv.x = f2bfu(o.x - bfu2f(hv.x));
        hv.y = f2bfu(o.y); lv.y = f2bfu(o.y - bfu2f(hv.y));
        hv.z = f2bfu(o.z); lv.z = f2bfu(o.z - bfu2f(hv.z));
        hv.w = f2bfu(o.w); lv.w = f2bfu(o.w - bfu2f(hv.w));
        size_t oo = (n0 + j) * D_ + d0;
        *(ushort4*)(sh + oo) = hv;
        *(ushort4*)(sl + oo) = lv;
        float4 xv = v[3 + j];
        uint2 xpk; xpk.x = pkbf(xv.x, xv.y); xpk.y = pkbf(xv.z, xv.w);
        *(uint2*)(xb + oo) = xpk;
    }
}

// ---------------- weight cast fp32 -> bf16 ----------------
__global__ __launch_bounds__(256) void k_castw(
    const float* __restrict__ s0, const float* __restrict__ s1,
    const float* __restrict__ s2, const float* __restrict__ s3,
    unsigned short* __restrict__ d0, unsigned short* __restrict__ d1,
    unsigned short* __restrict__ d2, unsigned short* __restrict__ d3)
{
    int which = blockIdx.x >> 8;
    int idx = ((blockIdx.x & 255) * 256 + threadIdx.x) * 4;
    const float* s = which == 0 ? s0 : which == 1 ? s1 : which == 2 ? s2 : s3;
    unsigned short* d = which == 0 ? d0 : which == 1 ? d1 : which == 2 ? d2 : d3;
    float4 v = *(const float4*)(s + idx);
    uint2 o;
    o.x = pkbf(v.x, v.y);
    o.y = pkbf(v.z, v.w);
    *(uint2*)(d + idx) = o;
}

// ---------------- GEMM1+2 merged: 64x64 tiles, BK=64, 3 blocks/CU --------
// grid (6, 128): x = panel (0..3 -> rkmg cols y*64; 4,5 -> t1b). BK=64 gives
// 8 MFMA/wave per barrier period (2x the BK=32 version, half the barriers).
__global__ __launch_bounds__(256) void k_gemm12(
    const unsigned short* __restrict__ sbf, const unsigned short* __restrict__ xb,
    const unsigned short* __restrict__ Wcatb, const unsigned short* __restrict__ w0b,
    float* __restrict__ rkmg, unsigned short* __restrict__ t1b)
{
    __shared__ __align__(16) unsigned short As[2][64 * 72];   // 64 rows x (64k+8pad)
    __shared__ __align__(16) unsigned short Bs[2][64 * 72];
    int tid = threadIdx.x;
    int y = blockIdx.x;                   // panel 0..5
    int n0 = blockIdx.y * 64;
    const unsigned short* A = (y < 4) ? sbf : xb;
    const unsigned short* Bp = (y < 4) ? (Wcatb + (size_t)y * 64 * 2048)
                                       : (w0b + (size_t)(y - 4) * 64 * 2048);
    int wave = tid >> 6, lane = tid & 63;
    int quad = lane >> 4, lcol = lane & 15;
    int wrow = (wave >> 1) * 32, wcol = (wave & 1) * 32;
    int r0 = tid >> 2, sub = (tid & 3) * 16;
    const unsigned short* ap = A + (size_t)(n0 + r0) * 2048 + sub;
    const unsigned short* bp = Bp + (size_t)r0 * 2048 + sub;
    int sidx = r0 * 72 + sub;

    f32x4 acc[2][2];
#pragma unroll
    for (int i = 0; i < 2; i++)
#pragma unroll
        for (int j = 0; j < 2; j++) acc[i][j] = {0.f, 0.f, 0.f, 0.f};

    {   // step 0 -> buf0
        uint4 a0 = *(const uint4*)ap, a1 = *(const uint4*)(ap + 8);
        uint4 b0 = *(const uint4*)bp, b1 = *(const uint4*)(bp + 8);
        *(uint4*)&As[0][sidx] = a0; *(uint4*)&As[0][sidx + 8] = a1;
        *(uint4*)&Bs[0][sidx] = b0; *(uint4*)&Bs[0][sidx + 8] = b1;
    }
    // preload step 1
    uint4 a0n = *(const uint4*)(ap + 64), a1n = *(const uint4*)(ap + 72);
    uint4 b0n = *(const uint4*)(bp + 64), b1n = *(const uint4*)(bp + 72);
    BAR();

    for (int kk = 0; kk < 32; kk++) {
        int cur = kk & 1;
#pragma unroll
        for (int s = 0; s < 2; s++) {
            short8 af0 = *(short8*)&As[cur][(wrow + lcol) * 72 + s * 32 + quad * 8];
            short8 af1 = *(short8*)&As[cur][(wrow + 16 + lcol) * 72 + s * 32 + quad * 8];
            short8 bf0 = *(short8*)&Bs[cur][(wcol + lcol) * 72 + s * 32 + quad * 8];
            short8 bf1 = *(short8*)&Bs[cur][(wcol + 16 + lcol) * 72 + s * 32 + quad * 8];
            acc[0][0] = MFMA(af0, bf0, acc[0][0]);
            acc[0][1] = MFMA(af0, bf1, acc[0][1]);
            acc[1][0] = MFMA(af1, bf0, acc[1][0]);
            acc[1][1] = MFMA(af1, bf1, acc[1][1]);
        }
        if (kk + 1 < 32) {
            int nb = cur ^ 1;
            *(uint4*)&As[nb][sidx] = a0n; *(uint4*)&As[nb][sidx + 8] = a1n;
            *(uint4*)&Bs[nb][sidx] = b0n; *(uint4*)&Bs[nb][sidx + 8] = b1n;
        }
        if (kk + 2 < 32) {
            int k0 = (kk + 2) * 64;
            a0n = *(const uint4*)(ap + k0); a1n = *(const uint4*)(ap + k0 + 8);
            b0n = *(const uint4*)(bp + k0); b1n = *(const uint4*)(bp + k0 + 8);
        }
        BAR();
    }

#pragma unroll
    for (int i = 0; i < 2; i++)
#pragma unroll
        for (int j = 0; j < 2; j++)
#pragma unroll
            for (int q = 0; q < 4; q++) {
                int row = wrow + i * 16 + quad * 4 + q;
                int col = wcol + j * 16 + lcol;
                int n = n0 + row;
                if (y < 4) rkmg[(size_t)n * 256 + y * 64 + col] = acc[i][j][q];
                else       t1b[(size_t)n * 128 + (y - 4) * 64 + col] = f2bfu(acc[i][j][q]);
            }
}

// ---------------- GEMM3: u = sigmoid(t1b @ w1^T + b1) * x --------------
__global__ __launch_bounds__(256) void k_gemm3(
    const unsigned short* __restrict__ t1b, const unsigned short* __restrict__ w1b,
    const float* __restrict__ b1, const float* __restrict__ x,
    float* __restrict__ u)
{
    __shared__ __align__(16) unsigned short As[2][128 * 32];
    __shared__ __align__(16) unsigned short Bs[2][128 * 32];
    int tid = threadIdx.x;
    int n0 = blockIdx.x * 128;
    int jblk = blockIdx.y * 128;
    int wave = tid >> 6, lane = tid & 63;
    int quad = lane >> 4, lcol = lane & 15;
    int wrow = (wave >> 1) * 64, wcol = (wave & 1) * 64;
    int r0 = tid >> 2;
    int sub = (tid & 3) * 8;
    const unsigned short* a0p = t1b + (size_t)(n0 + r0) * 128 + sub;
    const unsigned short* a1p = t1b + (size_t)(n0 + r0 + 64) * 128 + sub;
    const unsigned short* b0p = w1b + (size_t)(jblk + r0) * 128 + sub;
    const unsigned short* b1p = w1b + (size_t)(jblk + r0 + 64) * 128 + sub;

    f32x4 acc[4][4];
#pragma unroll
    for (int i = 0; i < 4; i++)
#pragma unroll
        for (int j = 0; j < 4; j++) acc[i][j] = {0.f, 0.f, 0.f, 0.f};

    uint4 av0 = *(const uint4*)a0p, av1 = *(const uint4*)a1p;
    uint4 bv0 = *(const uint4*)b0p, bv1 = *(const uint4*)b1p;
    {
        int i0 = tid * 8, i1 = 2048 + tid * 8;
        *(uint4*)&As[0][i0] = av0; *(uint4*)&As[0][i1] = av1;
        *(uint4*)&Bs[0][i0] = bv0; *(uint4*)&Bs[0][i1] = bv1;
    }
    av0 = *(const uint4*)(a0p + 32); av1 = *(const uint4*)(a1p + 32);
    bv0 = *(const uint4*)(b0p + 32); bv1 = *(const uint4*)(b1p + 32);
    BAR();

    for (int k32 = 0; k32 < 4; k32++) {
        int cur = k32 & 1;
        short8 af[4], bfr[4];
#pragma unroll
        for (int i = 0; i < 4; i++)
            af[i] = *(short8*)&As[cur][(wrow + i * 16 + lcol) * 32 + quad * 8];
#pragma unroll
        for (int j = 0; j < 4; j++)
            bfr[j] = *(short8*)&Bs[cur][(wcol + j * 16 + lcol) * 32 + quad * 8];
#pragma unroll
        for (int i = 0; i < 4; i++)
#pragma unroll
            for (int j = 0; j < 4; j++)
                acc[i][j] = MFMA(af[i], bfr[j], acc[i][j]);
        if (k32 + 1 < 4) {
            int nb = cur ^ 1;
            int i0 = tid * 8, i1 = 2048 + tid * 8;
            *(uint4*)&As[nb][i0] = av0; *(uint4*)&As[nb][i1] = av1;
            *(uint4*)&Bs[nb][i0] = bv0; *(uint4*)&Bs[nb][i1] = bv1;
        }
        if (k32 + 2 < 4) {
            int k0 = (k32 + 2) * 32;
            av0 = *(const uint4*)(a0p + k0); av1 = *(const uint4*)(a1p + k0);
            bv0 = *(const uint4*)(b0p + k0); bv1 = *(const uint4*)(b1p + k0);
        }
        BAR();
    }

#pragma unroll
    for (int i = 0; i < 4; i++)
#pragma unroll
        for (int j = 0; j < 4; j++)
#pragma unroll
            for (int q = 0; q < 4; q++) {
                int row = wrow + i * 16 + quad * 4 + q;
                int col = wcol + j * 16 + lcol;
                int n = n0 + row, jc = jblk + col;
                float val = acc[i][j][q] + b1[jc];
                val = 1.f / (1.f + expf(-val));
                val *= x[(size_t)n * D_ + jc];
                u[(size_t)n * D_ + jc] = val;
            }
}

// ---------------- gate prep (C=32) + precomputed P ------------------------
__global__ __launch_bounds__(256) void k_prep(const float* __restrict__ rkmg,
    const float* __restrict__ mb,
    unsigned short* __restrict__ Rt, unsigned short* __restrict__ Kc,
    float* __restrict__ Ac, unsigned short* __restrict__ Pg)
{
    __shared__ float seg[4 * 64];
    __shared__ __align__(16) unsigned short rtL[32 * 72];
    __shared__ __align__(16) unsigned short kdL[32 * 72];
    int blk = blockIdx.x;                 // b*NCH + chunk
    int sg = threadIdx.x >> 6, mm = threadIdx.x & 63;
    int n0 = blk * C_ + sg * 8;

    float rr[8], kk[8], lamr[8];
    float csum = 0.f;
#pragma unroll
    for (int j = 0; j < 8; j++) {
        const float* row = rkmg + (size_t)(n0 + j) * 256;
        float r   = row[mm];
        float k   = row[64 + mm];
        float mg1 = row[128 + mm] + mb[mm];
        float mg2 = row[192 + mm] + mb[64 + mm];
        float sel = (mg1 > 20.f) ? mg1 : log1pf(expf(mg1));
        float tau = 1.f / (1.f + expf(-mg2));
        float it  = expf(tau * logf(sel));
        float g   = -sel * tau;
        float s2  = k * k;
#pragma unroll
        for (int off = 32; off >= 1; off >>= 1) s2 += __shfl_xor(s2, off, 64);
        float kn = k / fmaxf(sqrtf(s2), 1e-12f);
        rr[j] = r;
        kk[j] = kn * it;
        csum += g;
        lamr[j] = csum;
    }
    seg[sg * 64 + mm] = csum;
    __syncthreads();
    float off = 0.f, tot = 0.f;
#pragma unroll
    for (int s = 0; s < 4; s++) {
        float v = seg[s * 64 + mm];
        if (s < sg) off += v;
        tot += v;
    }
    size_t obase = (size_t)blk * (C_ * 64);
    unsigned short kcp[8];
#pragma unroll
    for (int j = 0; j < 8; j++) {
        float lam = off + lamr[j];
        unsigned short rv = f2bfu(rr[j] * expf(lam));
        unsigned short kv = f2bfu(kk[j] * expf(-lam));
        int t = sg * 8 + j;
        Rt[obase + (size_t)t * 64 + mm] = rv;
        rtL[t * 72 + mm] = rv;
        kdL[t * 72 + mm] = kv;
        kcp[j] = f2bfu(kk[j] * expf(tot - lam));
    }
    ushort4 ka4, kb4;
    ka4.x = kcp[0]; ka4.y = kcp[1]; ka4.z = kcp[2]; ka4.w = kcp[3];
    kb4.x = kcp[4]; kb4.y = kcp[5]; kb4.z = kcp[6]; kb4.w = kcp[7];
    *(ushort4*)&Kc[obase + (size_t)mm * C_ + sg * 8]     = ka4;
    *(ushort4*)&Kc[obase + (size_t)mm * C_ + sg * 8 + 4] = kb4;
    if (sg == 0) Ac[(size_t)blk * 64 + mm] = expf(tot);
    __syncthreads();

    int lane = threadIdx.x & 63, quad = lane >> 4, l15 = lane & 15;
    size_t pb = (size_t)blk * 1024;
    if (sg < 3) {
        int ti = (sg == 0) ? 0 : 16;
        int si = (sg == 2) ? 16 : 0;
        short8 a0 = *(const short8*)&rtL[(ti + l15) * 72 + quad * 8];
        short8 a1 = *(const short8*)&rtL[(ti + l15) * 72 + 32 + quad * 8];
        short8 b0 = *(const short8*)&kdL[(si + l15) * 72 + quad * 8];
        short8 b1 = *(const short8*)&kdL[(si + l15) * 72 + 32 + quad * 8];
        f32x4 pp = {0.f, 0.f, 0.f, 0.f};
        pp = MFMA(a0, b0, pp);
        pp = MFMA(a1, b1, pp);
#pragma unroll
        for (int q = 0; q < 4; q++) {
            int t = ti + quad * 4 + q, s = si + l15;
            Pg[pb + t * 32 + s] = f2bfu((s <= t) ? pp[q] : 0.f);
        }
    } else {
#pragma unroll
        for (int q = 0; q < 4; q++)
            Pg[pb + (quad * 4 + q) * 32 + 16 + l15] = 0;
    }
}

// ---------------- chunked recurrence: 16-d slices, 2 blocks/CU -----------
// grid 512 = B(4) x slice(128, 16-d each), 4 waves/block -> 8 waves/CU from
// TWO independent barrier domains: when one block stalls at BAR, the other
// block's waves on the same SIMD issue (latency hiding across domains).
// wave0/1: O for token-tile 0/1 (6 MFMA each); wave2/3: S-update for m-half
// (2 sreg tiles, 4 MFMA each) + bf16 hi/lo mirror to ST. One BAR per chunk.
#define STAGE(q) do { \
    int t_ = tid >> 3, m8_ = (tid & 7) * 8; \
    *(uint4*)&rtS[q][t_ * 72 + m8_] = rtv; \
    int m_ = tid >> 2, s8_ = (tid & 3) * 8; \
    *(uint4*)&kcS[q][m_ * 40 + s8_] = kcv; \
    int s4_ = (tid & 7) * 4; \
    *(ushort4*)&PlS[q][t_ * 40 + s4_] = plv; \
    int dd_ = tid & 15, tt_ = tid >> 4; \
    _Pragma("unroll") \
    for (int j_ = 0; j_ < 2; j_++) { \
        unsigned short h_ = f2bfu(uv[j_]); \
        UTh[q][dd_ * 40 + tt_ + 16 * j_] = h_; \
        UTl[q][dd_ * 40 + tt_ + 16 * j_] = f2bfu(uv[j_] - bfu2f(h_)); \
    } \
    if (tid < 64) aCs[q][tid] = acv; \
} while (0)

#define PREFETCH(n) do { \
    size_t g_ = cbase + (size_t)(n) * 2048 + (size_t)tid * 8; \
    rtv = *(const uint4*)(Rt + g_); \
    kcv = *(const uint4*)(Kc + g_); \
    plv = *(const ushort4*)(Pg + pbase + (size_t)(n) * 1024 + tid * 4); \
    size_t un_ = ubase + (size_t)(n) * C_ * D_; \
    int dd_ = tid & 15, tt_ = tid >> 4; \
    uv[0] = u[un_ + (size_t)tt_ * D_ + dd_]; \
    uv[1] = u[un_ + (size_t)(tt_ + 16) * D_ + dd_]; \
    if (tid < 64) acv = Ac[(size_t)(bNCH + (n)) * 64 + tid]; \
} while (0)

__global__ __launch_bounds__(256) void k_chunk(
    const unsigned short* __restrict__ Rt, const unsigned short* __restrict__ Kc,
    const float* __restrict__ Ac, const unsigned short* __restrict__ Pg,
    const float* __restrict__ u, const unsigned short* __restrict__ sh,
    const unsigned short* __restrict__ sl,
    const float* __restrict__ rw, float* __restrict__ out)
{
    __shared__ __align__(16) unsigned short rtS[2][32 * 72];   // [t][m]
    __shared__ __align__(16) unsigned short PlS[2][32 * 40];   // [t][s]
    __shared__ __align__(16) unsigned short kcS[2][64 * 40];   // [m][s]
    __shared__ __align__(16) unsigned short UTh[2][16 * 40];   // [d][s]
    __shared__ __align__(16) unsigned short UTl[2][16 * 40];
    __shared__ __align__(16) unsigned short STh[2][16 * 72];   // [d][m]
    __shared__ __align__(16) unsigned short STl[2][16 * 72];
    __shared__ __align__(16) float aCs[2][64];

    int tid = threadIdx.x;
    int wave = tid >> 6, lane = tid & 63;
    int quad = lane >> 4, l15 = lane & 15;
    int b = blockIdx.x & 3, slice = blockIdx.x >> 2;   // slice 0..127
    int d0 = slice * 16;
    int bNCH = b * NCH;

    for (int i = tid; i < 2 * 16 * 72; i += 256) {
        (&STh[0][0])[i] = 0; (&STl[0][0])[i] = 0;
    }

    size_t cbase = (size_t)b * (L_ * 64);
    size_t pbase = (size_t)bNCH * 1024;
    size_t ubase = (size_t)b * L_ * D_ + d0;

    float rwv = (wave < 2) ? rw[d0 + l15] : 0.f;
    int ttile = wave;                     // O-wave token tile (0 or 1)

    uint4 rtv, kcv;
    ushort4 plv;
    float uv[2], acv = 0.f;
    unsigned short svh[4], svl[4], svhn[4], svln[4];
    size_t sadr = ubase + (size_t)(ttile * 16 + quad * 4) * D_ + l15;

    PREFETCH(0);
    STAGE(0);
    PREFETCH(1);
    if (wave < 2) {
#pragma unroll
        for (int q = 0; q < 4; q++) {
            svh[q] = sh[sadr + (size_t)q * D_];
            svl[q] = sl[sadr + (size_t)q * D_];
        }
    }
    BAR();   // zero-init + stage(0) visible

    f32x4 zz = {0.f, 0.f, 0.f, 0.f};
    f32x4 sreg[2];                        // S-waves: 2 m-tiles each
    sreg[0] = zz; sreg[1] = zz;

    for (int c = 0; c < NCH; c++) {
        int p = c & 1;
        if (c + 1 < NCH) STAGE(p ^ 1);
        if (c + 2 < NCH) PREFETCH(c + 2);

        if (wave < 2) {
            // ---- O-wave: one 16-token tile, full 16-d slice ----
            if (c + 1 < NCH) {
                size_t s0_ = sadr + (size_t)(c + 1) * C_ * D_;
#pragma unroll
                for (int q = 0; q < 4; q++) {
                    svhn[q] = sh[s0_ + (size_t)q * D_];
                    svln[q] = sl[s0_ + (size_t)q * D_];
                }
            }
            short8 a0 = *(const short8*)&rtS[p][(ttile * 16 + l15) * 72 + quad * 8];
            short8 a1 = *(const short8*)&rtS[p][(ttile * 16 + l15) * 72 + 32 + quad * 8];
            const unsigned short* sbh = &STh[p ^ 1][l15 * 72];
            const unsigned short* sbl = &STl[p ^ 1][l15 * 72];
            short8 sh0 = *(const short8*)&sbh[quad * 8];
            short8 sh1 = *(const short8*)&sbh[32 + quad * 8];
            short8 sl0 = *(const short8*)&sbl[quad * 8];
            short8 sl1 = *(const short8*)&sbl[32 + quad * 8];
            short8 pa = *(const short8*)&PlS[p][(ttile * 16 + l15) * 40 + quad * 8];
            short8 uh = *(const short8*)&UTh[p][l15 * 40 + quad * 8];
            short8 ul = *(const short8*)&UTl[p][l15 * 40 + quad * 8];
            __builtin_amdgcn_s_setprio(1);
            f32x4 oA = MFMA(a0, sh0, zz); oA = MFMA(a1, sh1, oA); oA = MFMA(pa, uh, oA);
            f32x4 oB = MFMA(a0, sl0, zz); oB = MFMA(a1, sl1, oB); oB = MFMA(pa, ul, oB);
            __builtin_amdgcn_s_setprio(0);
            size_t oa = ubase + (size_t)(c * C_ + ttile * 16 + quad * 4) * D_ + l15;
#pragma unroll
            for (int q = 0; q < 4; q++) {
                float rv = bfu2f(svh[q]) + bfu2f(svl[q]);
                out[oa + (size_t)q * D_] = SCALE_ * (oA[q] + oB[q]) + rv * rwv;
            }
#pragma unroll
            for (int q = 0; q < 4; q++) { svh[q] = svhn[q]; svl[q] = svln[q]; }
        } else {
            // ---- S-wave: sreg = aC*sreg + kc@U for m-half; mirror -> ST[p]
            int mt0 = (wave - 2) * 2;
            short8 uh = *(const short8*)&UTh[p][l15 * 40 + quad * 8];
            short8 ul = *(const short8*)&UTl[p][l15 * 40 + quad * 8];
            __builtin_amdgcn_s_setprio(1);
#pragma unroll
            for (int i = 0; i < 2; i++) {
                int mt = mt0 + i;
                f32x4 a4 = *(const f32x4*)&aCs[p][mt * 16 + quad * 4];
                f32x4 s = sreg[i];
                s[0] *= a4[0]; s[1] *= a4[1]; s[2] *= a4[2]; s[3] *= a4[3];
                short8 ka = *(const short8*)&kcS[p][(mt * 16 + l15) * 40 + quad * 8];
                s = MFMA(ka, uh, s);
                s = MFMA(ka, ul, s);
                sreg[i] = s;
                unsigned hA = pkbf(s[0], s[1]);
                unsigned hB = pkbf(s[2], s[3]);
                float f0 = bfu2f((unsigned short)hA), f1 = bfu2f((unsigned short)(hA >> 16));
                float f2 = bfu2f((unsigned short)hB), f3 = bfu2f((unsigned short)(hB >> 16));
                unsigned lA = pkbf(s[0] - f0, s[1] - f1);
                unsigned lB = pkbf(s[2] - f2, s[3] - f3);
                int sidx = l15 * 72 + mt * 16 + quad * 4;
                uint2 wh; wh.x = hA; wh.y = hB;
                uint2 wl; wl.x = lA; wl.y = lB;
                *(uint2*)&STh[p][sidx] = wh;
                *(uint2*)&STl[p][sidx] = wl;
            }
            __builtin_amdgcn_s_setprio(0);
        }
        BAR();   // stage(c+1) + ST[p] writes + all buf-p reads settled
    }
}

// ---------------- launcher ----------------
extern "C" void kernel_launch(void* const* d_in, const int* in_sizes, int n_in,
                              void* d_out, int out_size, void* d_ws, size_t ws_size,
                              hipStream_t stream)
{
    const float* x   = (const float*)d_in[0];
    const float* cw  = (const float*)d_in[1];
    const float* cb  = (const float*)d_in[2];
    const float* ipw = (const float*)d_in[3];
    const float* w0  = (const float*)d_in[4];
    const float* w1  = (const float*)d_in[5];
    const float* b1  = (const float*)d_in[6];
    const float* mw  = (const float*)d_in[7];
    const float* mb  = (const float*)d_in[8];
    const float* rw  = (const float*)d_in[9];
    float* out = (float*)d_out;

    unsigned short* sh = (unsigned short*)d_ws;          // NTOK*D bf16 (shift hi)
    unsigned short* sl = sh + (size_t)NTOK * D_;         // NTOK*D bf16 (shift lo)
    unsigned short* xb = sl + (size_t)NTOK * D_;         // NTOK*D bf16 (dead after gemm12)
    float* u = (float*)xb;                               // NTOK*D f32, overlays xb + next
    float* rkmg = u + (size_t)NTOK * D_;                 // NTOK*256
    float* Ac   = rkmg + (size_t)NTOK * 256;             // B*NCH*64
    unsigned short* Rt  = (unsigned short*)(Ac + (size_t)B_ * NCH * 64);
    unsigned short* Kc  = Rt + (size_t)NTOK * 64;
    unsigned short* Pg  = Kc + (size_t)NTOK * 64;        // B*NCH*1024
    unsigned short* t1b = Pg + (size_t)B_ * NCH * 1024;  // NTOK*128
    unsigned short* Wcatb = t1b + (size_t)NTOK * 128;
    unsigned short* w0b   = Wcatb + 256 * 2048;
    unsigned short* w1b   = w0b + 128 * 2048;

    k_conv<<<(NTOK / 8) * (D_ / 4) / 256, 256, 0, stream>>>(x, cw, cb, sh, sl, xb);

    k_castw<<<1024, 256, 0, stream>>>(ipw, mw, w0, w1,
                                      Wcatb, Wcatb + 128 * 2048, w0b, w1b);

    k_gemm12<<<dim3(6, 128), 256, 0, stream>>>(sh, xb, Wcatb, w0b, rkmg, t1b);

    k_prep<<<B_ * NCH, 256, 0, stream>>>(rkmg, mb, Rt, Kc, Ac, Pg);

    k_gemm3<<<dim3(64, 16), 256, 0, stream>>>(t1b, w1b, b1, x, u);

    k_chunk<<<512, 256, 0, stream>>>(Rt, Kc, Ac, Pg, u, sh, sl, rw, out);
}